// Round 1
// baseline (1797.602 us; speedup 1.0000x reference)
//
#include <hip/hip_runtime.h>
#include <math.h>

#define IN_C   128
#define HEADS  4
#define F1     128   // HEADS*HID
#define OUT_C  32
#define NEG    0.2f

// ---- monotonic float<->uint mapping for atomicMax on floats ----
__device__ __forceinline__ unsigned fmap(float f) {
    unsigned b = __float_as_uint(f);
    return (b & 0x80000000u) ? ~b : (b | 0x80000000u);
}
__device__ __forceinline__ float funmap(unsigned u) {
    return (u & 0x80000000u) ? __uint_as_float(u ^ 0x80000000u)
                             : __uint_as_float(~u);
}

// ============ layer-1 node transform: h1 = x@W1, a_s/a_d reductions ============
__global__ __launch_bounds__(256) void k_node1(
    const float* __restrict__ x, const float* __restrict__ W,
    const float* __restrict__ as_w, const float* __restrict__ ad_w,
    float* __restrict__ h1, float* __restrict__ as1, float* __restrict__ ad1, int n)
{
    __shared__ float Ws[IN_C * F1];       // 64 KB
    __shared__ float xs[32 * IN_C];       // 16 KB
    int t = threadIdx.x;
    for (int i = t; i < IN_C * F1; i += 256) Ws[i] = W[i];
    int n0 = blockIdx.x * 32;
    for (int i = t; i < 32 * IN_C; i += 256) {
        int nn = n0 + (i >> 7);
        xs[i] = (nn < n) ? x[(size_t)nn * IN_C + (i & 127)] : 0.f;
    }
    __syncthreads();
    int j = t & 127;
    float asw = as_w[j], adw = ad_w[j];
    for (int nl = t >> 7; nl < 32; nl += 2) {
        int nn = n0 + nl;
        if (nn >= n) break;
        const float* xr = &xs[nl * IN_C];
        float acc = 0.f;
        #pragma unroll
        for (int k = 0; k < IN_C; ++k) acc = fmaf(xr[k], Ws[k * F1 + j], acc);
        h1[(size_t)nn * F1 + j] = acc;
        float ps = acc * asw, pd = acc * adw;
        #pragma unroll
        for (int off = 16; off; off >>= 1) {
            ps += __shfl_down(ps, off, 32);
            pd += __shfl_down(pd, off, 32);
        }
        if ((j & 31) == 0) { as1[nn * HEADS + (j >> 5)] = ps; ad1[nn * HEADS + (j >> 5)] = pd; }
    }
}

// ============ layer-1 edge pass 1: segment max via atomicMax ============
__global__ __launch_bounds__(256) void k_edge1_max(
    const int* __restrict__ ei, const float* __restrict__ as1,
    const float* __restrict__ ad1, unsigned* __restrict__ m1, int E_, int n)
{
    int e = blockIdx.x * 256 + threadIdx.x;
    int EE = E_ + n;
    if (e >= EE) return;
    int s, d;
    if (e < E_) { s = ei[e]; d = ei[E_ + e]; } else { s = d = e - E_; }
    float4 av = *(const float4*)&as1[(size_t)s * 4];
    float4 bv = *(const float4*)&ad1[(size_t)d * 4];
    float eh[4] = {av.x + bv.x, av.y + bv.y, av.z + bv.z, av.w + bv.w};
    #pragma unroll
    for (int h = 0; h < 4; ++h) {
        float v = eh[h] > 0.f ? eh[h] : NEG * eh[h];
        atomicMax(&m1[(size_t)d * 4 + h], fmap(v));
    }
}

// ============ layer-1 edge pass 2: exp, denom atomicAdd, message scatter ======
// one wave (64 lanes) per edge; lane covers channels {lane, lane+64}
__global__ __launch_bounds__(256) void k_edge1_scatter(
    const int* __restrict__ ei, const float* __restrict__ as1,
    const float* __restrict__ ad1, const unsigned* __restrict__ m1,
    const float* __restrict__ h1,
    float* __restrict__ d1, float* __restrict__ acc1, int E_, int n)
{
    long long gid = (long long)blockIdx.x * 256 + threadIdx.x;
    int lane = threadIdx.x & 63;
    long long e = gid >> 6;
    int EE = E_ + n;
    if (e >= EE) return;
    int s, d;
    if (e < E_) { s = ei[e]; d = ei[E_ + e]; } else { s = d = (int)e - E_; }
    int ha = lane >> 5;  // 0/1
    float exv[2];
    #pragma unroll
    for (int q = 0; q < 2; ++q) {
        int h = ha + q * 2;
        float ev = as1[(size_t)s * 4 + h] + ad1[(size_t)d * 4 + h];
        ev = ev > 0.f ? ev : NEG * ev;
        exv[q] = expf(ev - funmap(m1[(size_t)d * 4 + h]));
    }
    if (lane < 4) {
        int h = lane;
        float ev = as1[(size_t)s * 4 + h] + ad1[(size_t)d * 4 + h];
        ev = ev > 0.f ? ev : NEG * ev;
        atomicAdd(&d1[(size_t)d * 4 + h], expf(ev - funmap(m1[(size_t)d * 4 + h])));
    }
    atomicAdd(&acc1[(size_t)d * F1 + lane],      h1[(size_t)s * F1 + lane]      * exv[0]);
    atomicAdd(&acc1[(size_t)d * F1 + 64 + lane], h1[(size_t)s * F1 + 64 + lane] * exv[1]);
}

// ============ normalize by denom + bias + ELU (in place) ============
__global__ __launch_bounds__(256) void k_norm_elu(
    float* __restrict__ z, const float* __restrict__ d1,
    const float* __restrict__ b1, int n)
{
    long long i = (long long)blockIdx.x * 256 + threadIdx.x;
    if (i >= (long long)n * F1) return;
    int nn = (int)(i >> 7), j = (int)(i & 127);
    float v = z[i] / d1[(size_t)nn * HEADS + (j >> 5)] + b1[j];
    z[i] = v > 0.f ? v : (expf(v) - 1.f);
}

// ============ layer-2 node transform: h2 = z@W2 ============
__global__ __launch_bounds__(256) void k_node2(
    const float* __restrict__ z, const float* __restrict__ W,
    const float* __restrict__ as_w, const float* __restrict__ ad_w,
    float* __restrict__ h2, float* __restrict__ as2, float* __restrict__ ad2, int n)
{
    __shared__ float Ws[IN_C * OUT_C];   // 16 KB
    __shared__ float zs[64 * IN_C];      // 32 KB
    int t = threadIdx.x;
    for (int i = t; i < IN_C * OUT_C; i += 256) Ws[i] = W[i];
    int n0 = blockIdx.x * 64;
    for (int i = t; i < 64 * IN_C; i += 256) {
        int nn = n0 + (i >> 7);
        zs[i] = (nn < n) ? z[(size_t)nn * IN_C + (i & 127)] : 0.f;
    }
    __syncthreads();
    int c = t & 31;
    float asw = as_w[c], adw = ad_w[c];
    for (int nl = t >> 5; nl < 64; nl += 8) {
        int nn = n0 + nl;
        if (nn >= n) break;
        const float* zr = &zs[nl * IN_C];
        float acc = 0.f;
        #pragma unroll
        for (int k = 0; k < IN_C; ++k) acc = fmaf(zr[k], Ws[k * OUT_C + c], acc);
        h2[(size_t)nn * OUT_C + c] = acc;
        float ps = acc * asw, pd = acc * adw;
        #pragma unroll
        for (int off = 16; off; off >>= 1) {
            ps += __shfl_down(ps, off, 32);
            pd += __shfl_down(pd, off, 32);
        }
        if (c == 0) { as2[nn] = ps; ad2[nn] = pd; }
    }
}

// ============ layer-2 edge pass 1 ============
__global__ __launch_bounds__(256) void k_edge2_max(
    const int* __restrict__ ei, const float* __restrict__ as2,
    const float* __restrict__ ad2, unsigned* __restrict__ m2, int E_, int n)
{
    int e = blockIdx.x * 256 + threadIdx.x;
    int EE = E_ + n;
    if (e >= EE) return;
    int s, d;
    if (e < E_) { s = ei[e]; d = ei[E_ + e]; } else { s = d = e - E_; }
    float ev = as2[s] + ad2[d];
    ev = ev > 0.f ? ev : NEG * ev;
    atomicMax(&m2[d], fmap(ev));
}

// ============ layer-2 edge pass 2: 32 threads per edge ============
__global__ __launch_bounds__(256) void k_edge2_scatter(
    const int* __restrict__ ei, const float* __restrict__ as2,
    const float* __restrict__ ad2, const unsigned* __restrict__ m2,
    const float* __restrict__ h2,
    float* __restrict__ d2, float* __restrict__ acc2, int E_, int n)
{
    long long idx = (long long)blockIdx.x * 256 + threadIdx.x;
    long long e = idx >> 5;
    int c = (int)(idx & 31);
    int EE = E_ + n;
    if (e >= EE) return;
    int s, d;
    if (e < E_) { s = ei[e]; d = ei[E_ + e]; } else { s = d = (int)e - E_; }
    float ev = as2[s] + ad2[d];
    ev = ev > 0.f ? ev : NEG * ev;
    float ex = expf(ev - funmap(m2[d]));
    if (c == 0) atomicAdd(&d2[d], ex);
    atomicAdd(&acc2[(size_t)d * OUT_C + c], h2[(size_t)s * OUT_C + c] * ex);
}

// ============ final: normalize + bias + log_softmax over 32 ch ============
__global__ __launch_bounds__(256) void k_logsoftmax(
    const float* __restrict__ acc2, const float* __restrict__ d2,
    const float* __restrict__ b2, float* __restrict__ y, int n)
{
    int t = threadIdx.x;
    int c = t & 31, nl = t >> 5;
    int nn = blockIdx.x * 8 + nl;
    if (nn >= n) return;
    float v = acc2[(size_t)nn * 32 + c] / d2[nn] + b2[c];
    float m = v;
    #pragma unroll
    for (int off = 16; off; off >>= 1) m = fmaxf(m, __shfl_xor(m, off, 32));
    float ex = expf(v - m);
    float ssum = ex;
    #pragma unroll
    for (int off = 16; off; off >>= 1) ssum += __shfl_xor(ssum, off, 32);
    y[(size_t)nn * 32 + c] = v - m - logf(ssum);
}

extern "C" void kernel_launch(void* const* d_in, const int* in_sizes, int n_in,
                              void* d_out, int out_size, void* d_ws, size_t ws_size,
                              hipStream_t stream) {
    const float* x    = (const float*)d_in[0];
    const int*   ei   = (const int*)d_in[1];
    const float* W1   = (const float*)d_in[2];
    const float* as1w = (const float*)d_in[3];
    const float* ad1w = (const float*)d_in[4];
    const float* b1   = (const float*)d_in[5];
    const float* W2   = (const float*)d_in[6];
    const float* as2w = (const float*)d_in[7];
    const float* ad2w = (const float*)d_in[8];
    const float* b2   = (const float*)d_in[9];
    float* out = (float*)d_out;

    int n  = in_sizes[0] / IN_C;
    int E_ = in_sizes[1] / 2;
    int EE = E_ + n;

    // ---- workspace layout ----
    // zero-block (one memset): m1[n*4] d1[n*4] acc1[n*128] m2[n] d2[n] acc2[n*32]
    // no-init:                 as1[n*4] ad1[n*4] h1[n*128] h2[n*32] as2[n] ad2[n]
    char* w = (char*)d_ws;
    size_t off = 0;
    auto take = [&](size_t elems) { void* p = w + off; off += ((elems * 4 + 255) & ~(size_t)255); return p; };
    unsigned* m1  = (unsigned*)take((size_t)n * 4);
    float* d1     = (float*)take((size_t)n * 4);
    float* acc1   = (float*)take((size_t)n * 128);   // becomes z after norm+ELU
    unsigned* m2  = (unsigned*)take((size_t)n);
    float* d2     = (float*)take((size_t)n);
    float* acc2   = (float*)take((size_t)n * 32);
    size_t zero_bytes = off;
    float* as1    = (float*)take((size_t)n * 4);
    float* ad1    = (float*)take((size_t)n * 4);
    float* h1     = (float*)take((size_t)n * 128);
    float* h2     = (float*)take((size_t)n * 32);
    float* as2    = (float*)take((size_t)n);
    float* ad2    = (float*)take((size_t)n);

    hipMemsetAsync(d_ws, 0, zero_bytes, stream);

    int g1 = (n + 31) / 32;
    k_node1<<<g1, 256, 0, stream>>>(x, W1, as1w, ad1w, h1, as1, ad1, n);

    int gE = (EE + 255) / 256;
    k_edge1_max<<<gE, 256, 0, stream>>>(ei, as1, ad1, m1, E_, n);

    int gS1 = (int)(((long long)EE * 64 + 255) / 256);
    k_edge1_scatter<<<gS1, 256, 0, stream>>>(ei, as1, ad1, m1, h1, d1, acc1, E_, n);

    int gNE = (int)(((long long)n * 128 + 255) / 256);
    k_norm_elu<<<gNE, 256, 0, stream>>>(acc1, d1, b1, n);

    int g2 = (n + 63) / 64;
    k_node2<<<g2, 256, 0, stream>>>(acc1, W2, as2w, ad2w, h2, as2, ad2, n);

    k_edge2_max<<<gE, 256, 0, stream>>>(ei, as2, ad2, m2, E_, n);

    int gS2 = (int)(((long long)EE * 32 + 255) / 256);
    k_edge2_scatter<<<gS2, 256, 0, stream>>>(ei, as2, ad2, m2, h2, d2, acc2, E_, n);

    int gLS = (n + 7) / 8;
    k_logsoftmax<<<gLS, 256, 0, stream>>>(acc2, d2, b2, out, n);
}

// Round 2
// 786.512 us; speedup vs baseline: 2.2855x; 2.2855x over previous
//
#include <hip/hip_runtime.h>
#include <math.h>

#define IN_C   128
#define HEADS  4
#define F1     128   // HEADS*HID
#define OUT_C  32
#define NEG    0.2f
#define CH1    128   // edge chunk per node-wave (layer 1)
#define CH2    128
#define SCAN_B 256

// ============ CSR build: histogram ============
__global__ __launch_bounds__(256) void k_hist(
    const int* __restrict__ ei, int* __restrict__ deg, int E_, int n)
{
    int e = blockIdx.x * 256 + threadIdx.x;
    int EE = E_ + n;
    if (e >= EE) return;
    int d = (e < E_) ? ei[E_ + e] : e - E_;
    atomicAdd(&deg[d], 1);
}

// ============ CSR build: block-level exclusive scan ============
__global__ __launch_bounds__(SCAN_B) void k_scan1(
    const int* __restrict__ deg, int* __restrict__ row_off,
    int* __restrict__ bsum, int n)
{
    __shared__ int sm[SCAN_B];
    int t = threadIdx.x;
    int i = blockIdx.x * SCAN_B + t;
    int v = (i < n) ? deg[i] : 0;
    sm[t] = v;
    __syncthreads();
    for (int off = 1; off < SCAN_B; off <<= 1) {
        int a = (t >= off) ? sm[t - off] : 0;
        __syncthreads();
        sm[t] += a;
        __syncthreads();
    }
    int inc = sm[t];
    if (i < n) row_off[i] = inc - v;              // exclusive within block
    if (t == SCAN_B - 1) bsum[blockIdx.x] = inc;  // block total
}

__global__ __launch_bounds__(1024) void k_scan2(int* __restrict__ bsum, int nb)
{
    __shared__ int sm[1024];
    int t = threadIdx.x;
    int v = (t < nb) ? bsum[t] : 0;
    sm[t] = v;
    __syncthreads();
    for (int off = 1; off < 1024; off <<= 1) {
        int a = (t >= off) ? sm[t - off] : 0;
        __syncthreads();
        sm[t] += a;
        __syncthreads();
    }
    if (t < nb) bsum[t] = sm[t] - v;              // exclusive
}

__global__ __launch_bounds__(256) void k_scan3(
    int* __restrict__ row_off, const int* __restrict__ bsum,
    int* __restrict__ cursor, int n, int EE)
{
    int i = blockIdx.x * 256 + threadIdx.x;
    if (i < n) {
        int st = row_off[i] + bsum[i >> 8];
        row_off[i] = st;
        cursor[i] = st;
    }
    if (i == 0) row_off[n] = EE;
}

// ============ CSR build: fill src lists ============
__global__ __launch_bounds__(256) void k_fill(
    const int* __restrict__ ei, int* __restrict__ cursor,
    int* __restrict__ csr, int E_, int n)
{
    int e = blockIdx.x * 256 + threadIdx.x;
    int EE = E_ + n;
    if (e >= EE) return;
    int s, d;
    if (e < E_) { s = ei[e]; d = ei[E_ + e]; } else { s = d = e - E_; }
    int p = atomicAdd(&cursor[d], 1);
    csr[p] = s;
}

// ============ layer-1 node transform: h1 = x@W1, a_s/a_d reductions ============
__global__ __launch_bounds__(256) void k_node1(
    const float* __restrict__ x, const float* __restrict__ W,
    const float* __restrict__ as_w, const float* __restrict__ ad_w,
    float* __restrict__ h1, float* __restrict__ as1, float* __restrict__ ad1, int n)
{
    __shared__ float Ws[IN_C * F1];       // 64 KB
    __shared__ float xs[32 * IN_C];       // 16 KB
    int t = threadIdx.x;
    for (int i = t; i < IN_C * F1; i += 256) Ws[i] = W[i];
    int n0 = blockIdx.x * 32;
    for (int i = t; i < 32 * IN_C; i += 256) {
        int nn = n0 + (i >> 7);
        xs[i] = (nn < n) ? x[(size_t)nn * IN_C + (i & 127)] : 0.f;
    }
    __syncthreads();
    int j = t & 127;
    float asw = as_w[j], adw = ad_w[j];
    for (int nl = t >> 7; nl < 32; nl += 2) {
        int nn = n0 + nl;
        if (nn >= n) break;
        const float* xr = &xs[nl * IN_C];
        float acc = 0.f;
        #pragma unroll
        for (int k = 0; k < IN_C; ++k) acc = fmaf(xr[k], Ws[k * F1 + j], acc);
        h1[(size_t)nn * F1 + j] = acc;
        float ps = acc * asw, pd = acc * adw;
        #pragma unroll
        for (int off = 16; off; off >>= 1) {
            ps += __shfl_down(ps, off, 32);
            pd += __shfl_down(pd, off, 32);
        }
        if ((j & 31) == 0) { as1[nn * HEADS + (j >> 5)] = ps; ad1[nn * HEADS + (j >> 5)] = pd; }
    }
}

// ============ fused layer-1 GAT: per-node softmax + gather + ELU ============
// one wave per dst node; lane covers channels {lane, lane+64}
__global__ __launch_bounds__(256) void k_gat1(
    const int* __restrict__ row_off, const int* __restrict__ csr,
    const float* __restrict__ as1, const float* __restrict__ ad1,
    const float* __restrict__ h1, const float* __restrict__ b1,
    float* __restrict__ z, int n)
{
    int w = threadIdx.x >> 6, lane = threadIdx.x & 63;
    int node = blockIdx.x * 4 + w;
    if (node >= n) return;
    __shared__ int   s_src_all[4][CH1];
    __shared__ float s_p_all[4][CH1 * 4];
    int* ssrc = s_src_all[w];
    float* sp = s_p_all[w];

    float add0 = ad1[(size_t)node * 4 + 0];
    float add1 = ad1[(size_t)node * 4 + 1];
    float add2 = ad1[(size_t)node * 4 + 2];
    float add3 = ad1[(size_t)node * 4 + 3];
    int beg = row_off[node], end = row_off[node + 1];
    int h0 = lane >> 5;   // my head pair: (h0, h0+2)

    float mr0 = -1e30f, mr1 = -1e30f, mr2 = -1e30f, mr3 = -1e30f;
    float sr0 = 0.f, sr1 = 0.f;
    float acc0 = 0.f, acc1 = 0.f;

    for (int c = beg; c < end; c += CH1) {
        int cnt = min(CH1, end - c);
        // ---- load + score into registers ----
        int sA = 0, sB = 0;
        float scA0=-1e30f, scA1=-1e30f, scA2=-1e30f, scA3=-1e30f;
        float scB0=-1e30f, scB1=-1e30f, scB2=-1e30f, scB3=-1e30f;
        bool hasA = lane < cnt, hasB = lane + 64 < cnt;
        if (hasA) {
            sA = csr[c + lane];
            ssrc[lane] = sA;
            float4 av = *(const float4*)&as1[(size_t)sA * 4];
            float v;
            v = av.x + add0; scA0 = v > 0.f ? v : NEG * v;
            v = av.y + add1; scA1 = v > 0.f ? v : NEG * v;
            v = av.z + add2; scA2 = v > 0.f ? v : NEG * v;
            v = av.w + add3; scA3 = v > 0.f ? v : NEG * v;
        }
        if (hasB) {
            sB = csr[c + lane + 64];
            ssrc[lane + 64] = sB;
            float4 av = *(const float4*)&as1[(size_t)sB * 4];
            float v;
            v = av.x + add0; scB0 = v > 0.f ? v : NEG * v;
            v = av.y + add1; scB1 = v > 0.f ? v : NEG * v;
            v = av.z + add2; scB2 = v > 0.f ? v : NEG * v;
            v = av.w + add3; scB3 = v > 0.f ? v : NEG * v;
        }
        // ---- chunk max per head, wave-reduce ----
        float lm0 = fmaxf(scA0, scB0), lm1 = fmaxf(scA1, scB1);
        float lm2 = fmaxf(scA2, scB2), lm3 = fmaxf(scA3, scB3);
        #pragma unroll
        for (int o = 32; o; o >>= 1) {
            lm0 = fmaxf(lm0, __shfl_xor(lm0, o));
            lm1 = fmaxf(lm1, __shfl_xor(lm1, o));
            lm2 = fmaxf(lm2, __shfl_xor(lm2, o));
            lm3 = fmaxf(lm3, __shfl_xor(lm3, o));
        }
        float nm0 = fmaxf(mr0, lm0), nm1 = fmaxf(mr1, lm1);
        float nm2 = fmaxf(mr2, lm2), nm3 = fmaxf(mr3, lm3);
        // ---- rescale my accumulators ----
        float omy0 = h0 ? mr1 : mr0, omy1 = h0 ? mr3 : mr2;
        float nmy0 = h0 ? nm1 : nm0, nmy1 = h0 ? nm3 : nm2;
        float r0 = __expf(omy0 - nmy0), r1 = __expf(omy1 - nmy1);
        acc0 *= r0; sr0 *= r0;
        acc1 *= r1; sr1 *= r1;
        // ---- convert scores -> probs in LDS, local denom sums ----
        float ls0 = 0.f, ls1 = 0.f, ls2 = 0.f, ls3 = 0.f;
        if (hasA) {
            float p0 = __expf(scA0 - nm0), p1 = __expf(scA1 - nm1);
            float p2 = __expf(scA2 - nm2), p3 = __expf(scA3 - nm3);
            sp[lane * 4 + 0] = p0; sp[lane * 4 + 1] = p1;
            sp[lane * 4 + 2] = p2; sp[lane * 4 + 3] = p3;
            ls0 += p0; ls1 += p1; ls2 += p2; ls3 += p3;
        }
        if (hasB) {
            float p0 = __expf(scB0 - nm0), p1 = __expf(scB1 - nm1);
            float p2 = __expf(scB2 - nm2), p3 = __expf(scB3 - nm3);
            sp[(lane + 64) * 4 + 0] = p0; sp[(lane + 64) * 4 + 1] = p1;
            sp[(lane + 64) * 4 + 2] = p2; sp[(lane + 64) * 4 + 3] = p3;
            ls0 += p0; ls1 += p1; ls2 += p2; ls3 += p3;
        }
        #pragma unroll
        for (int o = 32; o; o >>= 1) {
            ls0 += __shfl_xor(ls0, o);
            ls1 += __shfl_xor(ls1, o);
            ls2 += __shfl_xor(ls2, o);
            ls3 += __shfl_xor(ls3, o);
        }
        sr0 += h0 ? ls1 : ls0;
        sr1 += h0 ? ls3 : ls2;
        __threadfence_block();   // make LDS writes visible across the wave
        // ---- accumulate: coalesced gather of h1 rows ----
        #pragma unroll 2
        for (int j = 0; j < cnt; ++j) {
            int src = ssrc[j];
            float p0 = sp[j * 4 + h0];
            float p1 = sp[j * 4 + h0 + 2];
            const float* hr = h1 + (size_t)src * F1;
            acc0 = fmaf(p0, hr[lane], acc0);
            acc1 = fmaf(p1, hr[lane + 64], acc1);
        }
        mr0 = nm0; mr1 = nm1; mr2 = nm2; mr3 = nm3;
    }
    // ---- epilogue: normalize + bias + ELU ----
    float v0 = acc0 / sr0 + b1[lane];
    float v1 = acc1 / sr1 + b1[lane + 64];
    z[(size_t)node * F1 + lane]      = v0 > 0.f ? v0 : (__expf(v0) - 1.f);
    z[(size_t)node * F1 + 64 + lane] = v1 > 0.f ? v1 : (__expf(v1) - 1.f);
}

// ============ layer-2 node transform: h2 = z@W2 ============
__global__ __launch_bounds__(256) void k_node2(
    const float* __restrict__ z, const float* __restrict__ W,
    const float* __restrict__ as_w, const float* __restrict__ ad_w,
    float* __restrict__ h2, float* __restrict__ as2, float* __restrict__ ad2, int n)
{
    __shared__ float Ws[IN_C * OUT_C];   // 16 KB
    __shared__ float zs[64 * IN_C];      // 32 KB
    int t = threadIdx.x;
    for (int i = t; i < IN_C * OUT_C; i += 256) Ws[i] = W[i];
    int n0 = blockIdx.x * 64;
    for (int i = t; i < 64 * IN_C; i += 256) {
        int nn = n0 + (i >> 7);
        zs[i] = (nn < n) ? z[(size_t)nn * IN_C + (i & 127)] : 0.f;
    }
    __syncthreads();
    int c = t & 31;
    float asw = as_w[c], adw = ad_w[c];
    for (int nl = t >> 5; nl < 64; nl += 8) {
        int nn = n0 + nl;
        if (nn >= n) break;
        const float* zr = &zs[nl * IN_C];
        float acc = 0.f;
        #pragma unroll
        for (int k = 0; k < IN_C; ++k) acc = fmaf(zr[k], Ws[k * OUT_C + c], acc);
        h2[(size_t)nn * OUT_C + c] = acc;
        float ps = acc * asw, pd = acc * adw;
        #pragma unroll
        for (int off = 16; off; off >>= 1) {
            ps += __shfl_down(ps, off, 32);
            pd += __shfl_down(pd, off, 32);
        }
        if (c == 0) { as2[nn] = ps; ad2[nn] = pd; }
    }
}

// ============ fused layer-2 GAT + log_softmax ============
// one wave per dst node; lane = (edge parity, channel)
__global__ __launch_bounds__(256) void k_gat2(
    const int* __restrict__ row_off, const int* __restrict__ csr,
    const float* __restrict__ as2, const float* __restrict__ ad2,
    const float* __restrict__ h2, const float* __restrict__ b2,
    float* __restrict__ y, int n)
{
    int w = threadIdx.x >> 6, lane = threadIdx.x & 63;
    int node = blockIdx.x * 4 + w;
    if (node >= n) return;
    __shared__ int   s_src_all[4][CH2];
    __shared__ float s_p_all[4][CH2];
    int* ssrc = s_src_all[w];
    float* sp = s_p_all[w];

    float addv = ad2[node];
    int beg = row_off[node], end = row_off[node + 1];
    int c2 = lane & 31, eo = lane >> 5;
    float mr = -1e30f, sr = 0.f, acc = 0.f;

    for (int c = beg; c < end; c += CH2) {
        int cnt = min(CH2, end - c);
        float scA = -1e30f, scB = -1e30f;
        bool hasA = lane < cnt, hasB = lane + 64 < cnt;
        if (hasA) {
            int sA = csr[c + lane];
            ssrc[lane] = sA;
            float v = as2[sA] + addv;
            scA = v > 0.f ? v : NEG * v;
        }
        if (hasB) {
            int sB = csr[c + lane + 64];
            ssrc[lane + 64] = sB;
            float v = as2[sB] + addv;
            scB = v > 0.f ? v : NEG * v;
        }
        float lm = fmaxf(scA, scB);
        #pragma unroll
        for (int o = 32; o; o >>= 1) lm = fmaxf(lm, __shfl_xor(lm, o));
        float nm = fmaxf(mr, lm);
        float r = __expf(mr - nm);
        acc *= r; sr *= r;
        float ls = 0.f;
        if (hasA) { float p = __expf(scA - nm); sp[lane] = p; ls += p; }
        if (hasB) { float p = __expf(scB - nm); sp[lane + 64] = p; ls += p; }
        #pragma unroll
        for (int o = 32; o; o >>= 1) ls += __shfl_xor(ls, o);
        sr += ls;
        __threadfence_block();
        #pragma unroll 2
        for (int j = eo; j < cnt; j += 2) {
            int src = ssrc[j];
            acc = fmaf(sp[j], h2[(size_t)src * OUT_C + c2], acc);
        }
        mr = nm;
    }
    acc += __shfl_xor(acc, 32);   // fold the two edge-parity halves
    float v = acc / sr + b2[c2];
    // log_softmax over the 32 channels (both halves compute identically)
    float m = v;
    #pragma unroll
    for (int o = 16; o; o >>= 1) m = fmaxf(m, __shfl_xor(m, o));
    float ex = __expf(v - m), ss = ex;
    #pragma unroll
    for (int o = 16; o; o >>= 1) ss += __shfl_xor(ss, o);
    if (lane < 32) y[(size_t)node * OUT_C + c2] = v - m - logf(ss);
}

extern "C" void kernel_launch(void* const* d_in, const int* in_sizes, int n_in,
                              void* d_out, int out_size, void* d_ws, size_t ws_size,
                              hipStream_t stream) {
    const float* x    = (const float*)d_in[0];
    const int*   ei   = (const int*)d_in[1];
    const float* W1   = (const float*)d_in[2];
    const float* as1w = (const float*)d_in[3];
    const float* ad1w = (const float*)d_in[4];
    const float* b1   = (const float*)d_in[5];
    const float* W2   = (const float*)d_in[6];
    const float* as2w = (const float*)d_in[7];
    const float* ad2w = (const float*)d_in[8];
    const float* b2   = (const float*)d_in[9];
    float* out = (float*)d_out;

    int n  = in_sizes[0] / IN_C;
    int E_ = in_sizes[1] / 2;
    int EE = E_ + n;

    // ---- workspace layout ----
    char* w = (char*)d_ws;
    size_t off = 0;
    auto take = [&](size_t elems) { void* p = w + off; off += ((elems * 4 + 255) & ~(size_t)255); return p; };
    int* deg     = (int*)take((size_t)n);          // must be zeroed
    int* row_off = (int*)take((size_t)n + 1);
    int* cursor  = (int*)take((size_t)n);
    int* bsum    = (int*)take(1024);
    int* csr     = (int*)take((size_t)EE);
    float* as1   = (float*)take((size_t)n * 4);
    float* ad1   = (float*)take((size_t)n * 4);
    float* h1    = (float*)take((size_t)n * 128);
    float* z     = (float*)take((size_t)n * 128);
    float* h2    = (float*)take((size_t)n * 32);
    float* as2   = (float*)take((size_t)n);
    float* ad2   = (float*)take((size_t)n);

    hipMemsetAsync(deg, 0, (size_t)n * 4, stream);

    int gE = (EE + 255) / 256;
    int nb = (n + SCAN_B - 1) / SCAN_B;

    // CSR build (shared by both layers)
    k_hist<<<gE, 256, 0, stream>>>(ei, deg, E_, n);
    k_scan1<<<nb, SCAN_B, 0, stream>>>(deg, row_off, bsum, n);
    k_scan2<<<1, 1024, 0, stream>>>(bsum, nb);
    k_scan3<<<(n + 255) / 256, 256, 0, stream>>>(row_off, bsum, cursor, n, EE);
    k_fill<<<gE, 256, 0, stream>>>(ei, cursor, csr, E_, n);

    // layer 1
    int g1 = (n + 31) / 32;
    k_node1<<<g1, 256, 0, stream>>>(x, W1, as1w, ad1w, h1, as1, ad1, n);
    int gG = (n + 3) / 4;
    k_gat1<<<gG, 256, 0, stream>>>(row_off, csr, as1, ad1, h1, b1, z, n);

    // layer 2
    int g2 = (n + 63) / 64;
    k_node2<<<g2, 256, 0, stream>>>(z, W2, as2w, ad2w, h2, as2, ad2, n);
    k_gat2<<<gG, 256, 0, stream>>>(row_off, csr, as2, ad2, h2, b2, out, n);
}

// Round 3
// 605.245 us; speedup vs baseline: 2.9700x; 1.2995x over previous
//
#include <hip/hip_runtime.h>
#include <math.h>

#define IN_C   128
#define HEADS  4
#define F1     128   // HEADS*HID
#define OUT_C  32
#define NEG    0.2f
#define CH1    128   // edge chunk per node-wave (layer 1)
#define CH2    128
#define SCAN_B 256

// ============ CSR build: histogram ============
__global__ __launch_bounds__(256) void k_hist(
    const int* __restrict__ ei, int* __restrict__ deg, int E_, int n)
{
    int e = blockIdx.x * 256 + threadIdx.x;
    int EE = E_ + n;
    if (e >= EE) return;
    int d = (e < E_) ? ei[E_ + e] : e - E_;
    atomicAdd(&deg[d], 1);
}

// ============ CSR build: block-level exclusive scan ============
__global__ __launch_bounds__(SCAN_B) void k_scan1(
    const int* __restrict__ deg, int* __restrict__ row_off,
    int* __restrict__ bsum, int n)
{
    __shared__ int sm[SCAN_B];
    int t = threadIdx.x;
    int i = blockIdx.x * SCAN_B + t;
    int v = (i < n) ? deg[i] : 0;
    sm[t] = v;
    __syncthreads();
    for (int off = 1; off < SCAN_B; off <<= 1) {
        int a = (t >= off) ? sm[t - off] : 0;
        __syncthreads();
        sm[t] += a;
        __syncthreads();
    }
    int inc = sm[t];
    if (i < n) row_off[i] = inc - v;              // exclusive within block
    if (t == SCAN_B - 1) bsum[blockIdx.x] = inc;  // block total
}

__global__ __launch_bounds__(1024) void k_scan2(int* __restrict__ bsum, int nb)
{
    __shared__ int sm[1024];
    int t = threadIdx.x;
    int v = (t < nb) ? bsum[t] : 0;
    sm[t] = v;
    __syncthreads();
    for (int off = 1; off < 1024; off <<= 1) {
        int a = (t >= off) ? sm[t - off] : 0;
        __syncthreads();
        sm[t] += a;
        __syncthreads();
    }
    if (t < nb) bsum[t] = sm[t] - v;              // exclusive
}

__global__ __launch_bounds__(256) void k_scan3(
    int* __restrict__ row_off, const int* __restrict__ bsum,
    int* __restrict__ cursor, int n, int EE)
{
    int i = blockIdx.x * 256 + threadIdx.x;
    if (i < n) {
        int st = row_off[i] + bsum[i >> 8];
        row_off[i] = st;
        cursor[i] = st;
    }
    if (i == 0) row_off[n] = EE;
}

// ============ CSR build: fill src lists ============
__global__ __launch_bounds__(256) void k_fill(
    const int* __restrict__ ei, int* __restrict__ cursor,
    int* __restrict__ csr, int E_, int n)
{
    int e = blockIdx.x * 256 + threadIdx.x;
    int EE = E_ + n;
    if (e >= EE) return;
    int s, d;
    if (e < E_) { s = ei[e]; d = ei[E_ + e]; } else { s = d = e - E_; }
    int p = atomicAdd(&cursor[d], 1);
    csr[p] = s;
}

// ============ layer-1 GEMM: h1 = x@W1, register-tiled ============
// block: 256 thr = 16(tx: 4 cols each) x 16(ty: 4 nodes each); tile 64 nodes x 64 cols
// grid.x = 2*node_tiles; bit0 = col half
#define XS_STRIDE 68
__global__ __launch_bounds__(256) void k_gemm1(
    const float* __restrict__ x, const float* __restrict__ W,
    float* __restrict__ h1, int n)
{
    __shared__ float Ws[128 * 64];        // [k][64 cols]  32 KB
    __shared__ float xs[128 * XS_STRIDE]; // [k][64 nodes + pad] 34 KB
    int t = threadIdx.x;
    int half = blockIdx.x & 1;
    int n0 = (blockIdx.x >> 1) * 64;

    // stage W half: Ws[k][c] = W[k*128 + half*64 + c]
    for (int i = t; i < 128 * 16; i += 256) {
        int k = i >> 4, c4 = (i & 15) * 4;
        *(float4*)&Ws[k * 64 + c4] = *(const float4*)&W[k * 128 + half * 64 + c4];
    }
    // stage x tile transposed: xs[k][nl] = x[n0+nl][k]
    // nl in fast dim -> conflict-free LDS scatter; L1 absorbs the 16B-granular global reads
    for (int i = t; i < 64 * 32; i += 256) {
        int nl = i & 63, k4 = (i >> 6) * 4;
        int nn = n0 + nl;
        float4 v = (nn < n) ? *(const float4*)&x[(size_t)nn * 128 + k4]
                            : make_float4(0.f, 0.f, 0.f, 0.f);
        xs[(k4 + 0) * XS_STRIDE + nl] = v.x;
        xs[(k4 + 1) * XS_STRIDE + nl] = v.y;
        xs[(k4 + 2) * XS_STRIDE + nl] = v.z;
        xs[(k4 + 3) * XS_STRIDE + nl] = v.w;
    }
    __syncthreads();

    int tx = t & 15, ty = t >> 4;
    float acc[4][4] = {};
    #pragma unroll 8
    for (int k = 0; k < 128; ++k) {
        float4 a = *(float4*)&xs[k * XS_STRIDE + ty * 4];
        float4 b = *(float4*)&Ws[k * 64 + tx * 4];
        float av[4] = {a.x, a.y, a.z, a.w};
        float bv[4] = {b.x, b.y, b.z, b.w};
        #pragma unroll
        for (int i = 0; i < 4; ++i)
            #pragma unroll
            for (int j = 0; j < 4; ++j)
                acc[i][j] = fmaf(av[i], bv[j], acc[i][j]);
    }
    int cbase = half * 64 + tx * 4;
    #pragma unroll
    for (int i = 0; i < 4; ++i) {
        int nn = n0 + ty * 4 + i;
        if (nn < n)
            *(float4*)&h1[(size_t)nn * 128 + cbase] =
                make_float4(acc[i][0], acc[i][1], acc[i][2], acc[i][3]);
    }
}

// ============ layer-2 GEMM: h2 = z@W2 (N=32), register-tiled ============
// block: 256 thr = 8(tx: 4 cols) x 32(ty: 2 nodes); tile 64 nodes x 32 cols
#define ZS_STRIDE 66
__global__ __launch_bounds__(256) void k_gemm2(
    const float* __restrict__ z, const float* __restrict__ W,
    float* __restrict__ h2, int n)
{
    __shared__ float Ws[128 * 32];        // 16 KB
    __shared__ float zs[128 * ZS_STRIDE]; // 33 KB
    int t = threadIdx.x;
    int n0 = blockIdx.x * 64;

    for (int i = t; i < 128 * 8; i += 256) {
        int k = i >> 3, c4 = (i & 7) * 4;
        *(float4*)&Ws[k * 32 + c4] = *(const float4*)&W[k * 32 + c4];
    }
    for (int i = t; i < 64 * 32; i += 256) {
        int nl = i & 63, k4 = (i >> 6) * 4;
        int nn = n0 + nl;
        float4 v = (nn < n) ? *(const float4*)&z[(size_t)nn * 128 + k4]
                            : make_float4(0.f, 0.f, 0.f, 0.f);
        zs[(k4 + 0) * ZS_STRIDE + nl] = v.x;
        zs[(k4 + 1) * ZS_STRIDE + nl] = v.y;
        zs[(k4 + 2) * ZS_STRIDE + nl] = v.z;
        zs[(k4 + 3) * ZS_STRIDE + nl] = v.w;
    }
    __syncthreads();

    int tx = t & 7, ty = t >> 3;   // ty: 2 nodes each
    float acc[2][4] = {};
    #pragma unroll 8
    for (int k = 0; k < 128; ++k) {
        float2 a = *(float2*)&zs[k * ZS_STRIDE + ty * 2];
        float4 b = *(float4*)&Ws[k * 32 + tx * 4];
        float av[2] = {a.x, a.y};
        float bv[4] = {b.x, b.y, b.z, b.w};
        #pragma unroll
        for (int i = 0; i < 2; ++i)
            #pragma unroll
            for (int j = 0; j < 4; ++j)
                acc[i][j] = fmaf(av[i], bv[j], acc[i][j]);
    }
    #pragma unroll
    for (int i = 0; i < 2; ++i) {
        int nn = n0 + ty * 2 + i;
        if (nn < n)
            *(float4*)&h2[(size_t)nn * 32 + tx * 4] =
                make_float4(acc[i][0], acc[i][1], acc[i][2], acc[i][3]);
    }
}

// ============ attention coefficient reductions ============
// layer 1: one wave per node, 128 cols, 4 heads of 32
__global__ __launch_bounds__(256) void k_att1(
    const float* __restrict__ h1, const float* __restrict__ as_w,
    const float* __restrict__ ad_w, float* __restrict__ as1,
    float* __restrict__ ad1, int n)
{
    int w = threadIdx.x >> 6, lane = threadIdx.x & 63;
    int node = blockIdx.x * 4 + w;
    if (node >= n) return;
    float v0 = h1[(size_t)node * 128 + lane];
    float v1 = h1[(size_t)node * 128 + 64 + lane];
    float s0 = v0 * as_w[lane],      s1 = v1 * as_w[64 + lane];
    float d0 = v0 * ad_w[lane],      d1 = v1 * ad_w[64 + lane];
    #pragma unroll
    for (int o = 16; o; o >>= 1) {
        s0 += __shfl_xor(s0, o); s1 += __shfl_xor(s1, o);
        d0 += __shfl_xor(d0, o); d1 += __shfl_xor(d1, o);
    }
    if ((lane & 31) == 0) {
        int h = lane >> 5;
        as1[(size_t)node * 4 + h]     = s0;
        as1[(size_t)node * 4 + 2 + h] = s1;
        ad1[(size_t)node * 4 + h]     = d0;
        ad1[(size_t)node * 4 + 2 + h] = d1;
    }
}

// layer 2: 32 lanes per node
__global__ __launch_bounds__(256) void k_att2(
    const float* __restrict__ h2, const float* __restrict__ as_w,
    const float* __restrict__ ad_w, float* __restrict__ as2,
    float* __restrict__ ad2, int n)
{
    int g = threadIdx.x >> 5, c = threadIdx.x & 31;
    int node = blockIdx.x * 8 + g;
    if (node >= n) return;
    float v = h2[(size_t)node * 32 + c];
    float s = v * as_w[c], d = v * ad_w[c];
    #pragma unroll
    for (int o = 16; o; o >>= 1) { s += __shfl_xor(s, o); d += __shfl_xor(d, o); }
    if (c == 0) { as2[node] = s; ad2[node] = d; }
}

// ============ fused layer-1 GAT: per-node softmax + gather + ELU ============
// one wave per dst node; lane covers channels {lane, lane+64}
__global__ __launch_bounds__(256) void k_gat1(
    const int* __restrict__ row_off, const int* __restrict__ csr,
    const float* __restrict__ as1, const float* __restrict__ ad1,
    const float* __restrict__ h1, const float* __restrict__ b1,
    float* __restrict__ z, int n)
{
    int w = threadIdx.x >> 6, lane = threadIdx.x & 63;
    int node = blockIdx.x * 4 + w;
    if (node >= n) return;
    __shared__ int   s_src_all[4][CH1];
    __shared__ float s_p_all[4][CH1 * 4];
    int* ssrc = s_src_all[w];
    float* sp = s_p_all[w];

    float add0 = ad1[(size_t)node * 4 + 0];
    float add1 = ad1[(size_t)node * 4 + 1];
    float add2 = ad1[(size_t)node * 4 + 2];
    float add3 = ad1[(size_t)node * 4 + 3];
    int beg = row_off[node], end = row_off[node + 1];
    int h0 = lane >> 5;   // my head pair: (h0, h0+2)

    float mr0 = -1e30f, mr1 = -1e30f, mr2 = -1e30f, mr3 = -1e30f;
    float sr0 = 0.f, sr1 = 0.f;
    float acc0 = 0.f, acc1 = 0.f;

    for (int c = beg; c < end; c += CH1) {
        int cnt = min(CH1, end - c);
        int sA = 0, sB = 0;
        float scA0=-1e30f, scA1=-1e30f, scA2=-1e30f, scA3=-1e30f;
        float scB0=-1e30f, scB1=-1e30f, scB2=-1e30f, scB3=-1e30f;
        bool hasA = lane < cnt, hasB = lane + 64 < cnt;
        if (hasA) {
            sA = csr[c + lane];
            ssrc[lane] = sA;
            float4 av = *(const float4*)&as1[(size_t)sA * 4];
            float v;
            v = av.x + add0; scA0 = v > 0.f ? v : NEG * v;
            v = av.y + add1; scA1 = v > 0.f ? v : NEG * v;
            v = av.z + add2; scA2 = v > 0.f ? v : NEG * v;
            v = av.w + add3; scA3 = v > 0.f ? v : NEG * v;
        }
        if (hasB) {
            sB = csr[c + lane + 64];
            ssrc[lane + 64] = sB;
            float4 av = *(const float4*)&as1[(size_t)sB * 4];
            float v;
            v = av.x + add0; scB0 = v > 0.f ? v : NEG * v;
            v = av.y + add1; scB1 = v > 0.f ? v : NEG * v;
            v = av.z + add2; scB2 = v > 0.f ? v : NEG * v;
            v = av.w + add3; scB3 = v > 0.f ? v : NEG * v;
        }
        float lm0 = fmaxf(scA0, scB0), lm1 = fmaxf(scA1, scB1);
        float lm2 = fmaxf(scA2, scB2), lm3 = fmaxf(scA3, scB3);
        #pragma unroll
        for (int o = 32; o; o >>= 1) {
            lm0 = fmaxf(lm0, __shfl_xor(lm0, o));
            lm1 = fmaxf(lm1, __shfl_xor(lm1, o));
            lm2 = fmaxf(lm2, __shfl_xor(lm2, o));
            lm3 = fmaxf(lm3, __shfl_xor(lm3, o));
        }
        float nm0 = fmaxf(mr0, lm0), nm1 = fmaxf(mr1, lm1);
        float nm2 = fmaxf(mr2, lm2), nm3 = fmaxf(mr3, lm3);
        float omy0 = h0 ? mr1 : mr0, omy1 = h0 ? mr3 : mr2;
        float nmy0 = h0 ? nm1 : nm0, nmy1 = h0 ? nm3 : nm2;
        float r0 = __expf(omy0 - nmy0), r1 = __expf(omy1 - nmy1);
        acc0 *= r0; sr0 *= r0;
        acc1 *= r1; sr1 *= r1;
        float ls0 = 0.f, ls1 = 0.f, ls2 = 0.f, ls3 = 0.f;
        if (hasA) {
            float p0 = __expf(scA0 - nm0), p1 = __expf(scA1 - nm1);
            float p2 = __expf(scA2 - nm2), p3 = __expf(scA3 - nm3);
            sp[lane * 4 + 0] = p0; sp[lane * 4 + 1] = p1;
            sp[lane * 4 + 2] = p2; sp[lane * 4 + 3] = p3;
            ls0 += p0; ls1 += p1; ls2 += p2; ls3 += p3;
        }
        if (hasB) {
            float p0 = __expf(scB0 - nm0), p1 = __expf(scB1 - nm1);
            float p2 = __expf(scB2 - nm2), p3 = __expf(scB3 - nm3);
            sp[(lane + 64) * 4 + 0] = p0; sp[(lane + 64) * 4 + 1] = p1;
            sp[(lane + 64) * 4 + 2] = p2; sp[(lane + 64) * 4 + 3] = p3;
            ls0 += p0; ls1 += p1; ls2 += p2; ls3 += p3;
        }
        #pragma unroll
        for (int o = 32; o; o >>= 1) {
            ls0 += __shfl_xor(ls0, o);
            ls1 += __shfl_xor(ls1, o);
            ls2 += __shfl_xor(ls2, o);
            ls3 += __shfl_xor(ls3, o);
        }
        sr0 += h0 ? ls1 : ls0;
        sr1 += h0 ? ls3 : ls2;
        __threadfence_block();
        #pragma unroll 2
        for (int j = 0; j < cnt; ++j) {
            int src = ssrc[j];
            float p0 = sp[j * 4 + h0];
            float p1 = sp[j * 4 + h0 + 2];
            const float* hr = h1 + (size_t)src * F1;
            acc0 = fmaf(p0, hr[lane], acc0);
            acc1 = fmaf(p1, hr[lane + 64], acc1);
        }
        mr0 = nm0; mr1 = nm1; mr2 = nm2; mr3 = nm3;
    }
    float v0 = acc0 / sr0 + b1[lane];
    float v1 = acc1 / sr1 + b1[lane + 64];
    z[(size_t)node * F1 + lane]      = v0 > 0.f ? v0 : (__expf(v0) - 1.f);
    z[(size_t)node * F1 + 64 + lane] = v1 > 0.f ? v1 : (__expf(v1) - 1.f);
}

// ============ fused layer-2 GAT + log_softmax ============
__global__ __launch_bounds__(256) void k_gat2(
    const int* __restrict__ row_off, const int* __restrict__ csr,
    const float* __restrict__ as2, const float* __restrict__ ad2,
    const float* __restrict__ h2, const float* __restrict__ b2,
    float* __restrict__ y, int n)
{
    int w = threadIdx.x >> 6, lane = threadIdx.x & 63;
    int node = blockIdx.x * 4 + w;
    if (node >= n) return;
    __shared__ int   s_src_all[4][CH2];
    __shared__ float s_p_all[4][CH2];
    int* ssrc = s_src_all[w];
    float* sp = s_p_all[w];

    float addv = ad2[node];
    int beg = row_off[node], end = row_off[node + 1];
    int c2 = lane & 31, eo = lane >> 5;
    float mr = -1e30f, sr = 0.f, acc = 0.f;

    for (int c = beg; c < end; c += CH2) {
        int cnt = min(CH2, end - c);
        float scA = -1e30f, scB = -1e30f;
        bool hasA = lane < cnt, hasB = lane + 64 < cnt;
        if (hasA) {
            int sA = csr[c + lane];
            ssrc[lane] = sA;
            float v = as2[sA] + addv;
            scA = v > 0.f ? v : NEG * v;
        }
        if (hasB) {
            int sB = csr[c + lane + 64];
            ssrc[lane + 64] = sB;
            float v = as2[sB] + addv;
            scB = v > 0.f ? v : NEG * v;
        }
        float lm = fmaxf(scA, scB);
        #pragma unroll
        for (int o = 32; o; o >>= 1) lm = fmaxf(lm, __shfl_xor(lm, o));
        float nm = fmaxf(mr, lm);
        float r = __expf(mr - nm);
        acc *= r; sr *= r;
        float ls = 0.f;
        if (hasA) { float p = __expf(scA - nm); sp[lane] = p; ls += p; }
        if (hasB) { float p = __expf(scB - nm); sp[lane + 64] = p; ls += p; }
        #pragma unroll
        for (int o = 32; o; o >>= 1) ls += __shfl_xor(ls, o);
        sr += ls;
        __threadfence_block();
        #pragma unroll 2
        for (int j = eo; j < cnt; j += 2) {
            int src = ssrc[j];
            acc = fmaf(sp[j], h2[(size_t)src * OUT_C + c2], acc);
        }
        mr = nm;
    }
    acc += __shfl_xor(acc, 32);
    float v = acc / sr + b2[c2];
    float m = v;
    #pragma unroll
    for (int o = 16; o; o >>= 1) m = fmaxf(m, __shfl_xor(m, o));
    float ex = __expf(v - m), ss = ex;
    #pragma unroll
    for (int o = 16; o; o >>= 1) ss += __shfl_xor(ss, o);
    if (lane < 32) y[(size_t)node * OUT_C + c2] = v - m - logf(ss);
}

extern "C" void kernel_launch(void* const* d_in, const int* in_sizes, int n_in,
                              void* d_out, int out_size, void* d_ws, size_t ws_size,
                              hipStream_t stream) {
    const float* x    = (const float*)d_in[0];
    const int*   ei   = (const int*)d_in[1];
    const float* W1   = (const float*)d_in[2];
    const float* as1w = (const float*)d_in[3];
    const float* ad1w = (const float*)d_in[4];
    const float* b1   = (const float*)d_in[5];
    const float* W2   = (const float*)d_in[6];
    const float* as2w = (const float*)d_in[7];
    const float* ad2w = (const float*)d_in[8];
    const float* b2   = (const float*)d_in[9];
    float* out = (float*)d_out;

    int n  = in_sizes[0] / IN_C;
    int E_ = in_sizes[1] / 2;
    int EE = E_ + n;

    char* w = (char*)d_ws;
    size_t off = 0;
    auto take = [&](size_t elems) { void* p = w + off; off += ((elems * 4 + 255) & ~(size_t)255); return p; };
    int* deg     = (int*)take((size_t)n);          // must be zeroed
    int* row_off = (int*)take((size_t)n + 1);
    int* cursor  = (int*)take((size_t)n);
    int* bsum    = (int*)take(1024);
    int* csr     = (int*)take((size_t)EE);
    float* as1   = (float*)take((size_t)n * 4);
    float* ad1   = (float*)take((size_t)n * 4);
    float* h1    = (float*)take((size_t)n * 128);
    float* z     = (float*)take((size_t)n * 128);
    float* h2    = (float*)take((size_t)n * 32);
    float* as2   = (float*)take((size_t)n);
    float* ad2   = (float*)take((size_t)n);

    hipMemsetAsync(deg, 0, (size_t)n * 4, stream);

    int gE = (EE + 255) / 256;
    int nb = (n + SCAN_B - 1) / SCAN_B;

    // CSR build (shared by both layers)
    k_hist<<<gE, 256, 0, stream>>>(ei, deg, E_, n);
    k_scan1<<<nb, SCAN_B, 0, stream>>>(deg, row_off, bsum, n);
    k_scan2<<<1, 1024, 0, stream>>>(bsum, nb);
    k_scan3<<<(n + 255) / 256, 256, 0, stream>>>(row_off, bsum, cursor, n, EE);
    k_fill<<<gE, 256, 0, stream>>>(ei, cursor, csr, E_, n);

    // layer 1
    int nt = (n + 63) / 64;
    k_gemm1<<<nt * 2, 256, 0, stream>>>(x, W1, h1, n);
    k_att1<<<(n + 3) / 4, 256, 0, stream>>>(h1, as1w, ad1w, as1, ad1, n);
    int gG = (n + 3) / 4;
    k_gat1<<<gG, 256, 0, stream>>>(row_off, csr, as1, ad1, h1, b1, z, n);

    // layer 2
    k_gemm2<<<nt, 256, 0, stream>>>(z, W2, h2, n);
    k_att2<<<(n + 7) / 8, 256, 0, stream>>>(h2, as2w, ad2w, as2, ad2, n);
    k_gat2<<<gG, 256, 0, stream>>>(row_off, csr, as2, ad2, h2, b2, out, n);
}

// Round 5
// 548.338 us; speedup vs baseline: 3.2783x; 1.1038x over previous
//
#include <hip/hip_runtime.h>
#include <hip/hip_fp16.h>
#include <math.h>

#define IN_C   128
#define HEADS  4
#define F1     128   // HEADS*HID
#define OUT_C  32
#define NEG    0.2f
#define CH1    128   // edge chunk per node-wave (layer 1)
#define CH2    128
#define SCAN_B 256

// ---- fp16 helpers (RNE; e5m10 keeps ~8x more mantissa than bf16) ----
__device__ __forceinline__ unsigned short f2h(float f) {
    return __half_as_ushort(__float2half_rn(f));
}
__device__ __forceinline__ float h2f(unsigned short u) {
    return __half2float(__ushort_as_half(u));
}

// ============ CSR build: histogram ============
__global__ __launch_bounds__(256) void k_hist(
    const int* __restrict__ ei, int* __restrict__ deg, int E_, int n)
{
    int e = blockIdx.x * 256 + threadIdx.x;
    int EE = E_ + n;
    if (e >= EE) return;
    int d = (e < E_) ? ei[E_ + e] : e - E_;
    atomicAdd(&deg[d], 1);
}

// ============ CSR build: block-level exclusive scan ============
__global__ __launch_bounds__(SCAN_B) void k_scan1(
    const int* __restrict__ deg, int* __restrict__ row_off,
    int* __restrict__ bsum, int n)
{
    __shared__ int sm[SCAN_B];
    int t = threadIdx.x;
    int i = blockIdx.x * SCAN_B + t;
    int v = (i < n) ? deg[i] : 0;
    sm[t] = v;
    __syncthreads();
    for (int off = 1; off < SCAN_B; off <<= 1) {
        int a = (t >= off) ? sm[t - off] : 0;
        __syncthreads();
        sm[t] += a;
        __syncthreads();
    }
    int inc = sm[t];
    if (i < n) row_off[i] = inc - v;
    if (t == SCAN_B - 1) bsum[blockIdx.x] = inc;
}

__global__ __launch_bounds__(1024) void k_scan2(int* __restrict__ bsum, int nb)
{
    __shared__ int sm[1024];
    int t = threadIdx.x;
    int v = (t < nb) ? bsum[t] : 0;
    sm[t] = v;
    __syncthreads();
    for (int off = 1; off < 1024; off <<= 1) {
        int a = (t >= off) ? sm[t - off] : 0;
        __syncthreads();
        sm[t] += a;
        __syncthreads();
    }
    if (t < nb) bsum[t] = sm[t] - v;
}

__global__ __launch_bounds__(256) void k_scan3(
    int* __restrict__ row_off, const int* __restrict__ bsum,
    int* __restrict__ cursor, int n, int EE)
{
    int i = blockIdx.x * 256 + threadIdx.x;
    if (i < n) {
        int st = row_off[i] + bsum[i >> 8];
        row_off[i] = st;
        cursor[i] = st;
    }
    if (i == 0) row_off[n] = EE;
}

// ============ CSR build: fill src lists ============
__global__ __launch_bounds__(256) void k_fill(
    const int* __restrict__ ei, int* __restrict__ cursor,
    int* __restrict__ csr, int E_, int n)
{
    int e = blockIdx.x * 256 + threadIdx.x;
    int EE = E_ + n;
    if (e >= EE) return;
    int s, d;
    if (e < E_) { s = ei[e]; d = ei[E_ + e]; } else { s = d = e - E_; }
    int p = atomicAdd(&cursor[d], 1);
    csr[p] = s;
}

// ============ layer-1 GEMM: h1 = x@W1 (fp16 out), register-tiled ============
#define XS_STRIDE 68
__global__ __launch_bounds__(256) void k_gemm1(
    const float* __restrict__ x, const float* __restrict__ W,
    unsigned short* __restrict__ h1h, int n)
{
    __shared__ float Ws[128 * 64];
    __shared__ float xs[128 * XS_STRIDE];
    int t = threadIdx.x;
    int half = blockIdx.x & 1;
    int n0 = (blockIdx.x >> 1) * 64;

    for (int i = t; i < 128 * 16; i += 256) {
        int k = i >> 4, c4 = (i & 15) * 4;
        *(float4*)&Ws[k * 64 + c4] = *(const float4*)&W[k * 128 + half * 64 + c4];
    }
    for (int i = t; i < 64 * 32; i += 256) {
        int nl = i & 63, k4 = (i >> 6) * 4;
        int nn = n0 + nl;
        float4 v = (nn < n) ? *(const float4*)&x[(size_t)nn * 128 + k4]
                            : make_float4(0.f, 0.f, 0.f, 0.f);
        xs[(k4 + 0) * XS_STRIDE + nl] = v.x;
        xs[(k4 + 1) * XS_STRIDE + nl] = v.y;
        xs[(k4 + 2) * XS_STRIDE + nl] = v.z;
        xs[(k4 + 3) * XS_STRIDE + nl] = v.w;
    }
    __syncthreads();

    int tx = t & 15, ty = t >> 4;
    float acc[4][4] = {};
    #pragma unroll 8
    for (int k = 0; k < 128; ++k) {
        float4 a = *(float4*)&xs[k * XS_STRIDE + ty * 4];
        float4 b = *(float4*)&Ws[k * 64 + tx * 4];
        float av[4] = {a.x, a.y, a.z, a.w};
        float bv[4] = {b.x, b.y, b.z, b.w};
        #pragma unroll
        for (int i = 0; i < 4; ++i)
            #pragma unroll
            for (int j = 0; j < 4; ++j)
                acc[i][j] = fmaf(av[i], bv[j], acc[i][j]);
    }
    int cbase = half * 64 + tx * 4;
    #pragma unroll
    for (int i = 0; i < 4; ++i) {
        int nn = n0 + ty * 4 + i;
        if (nn < n) {
            ushort4 p;
            p.x = f2h(acc[i][0]); p.y = f2h(acc[i][1]);
            p.z = f2h(acc[i][2]); p.w = f2h(acc[i][3]);
            *(ushort4*)&h1h[(size_t)nn * 128 + cbase] = p;
        }
    }
}

// ============ layer-2 GEMM: h2 = z@W2 (fp16 out) ============
#define ZS_STRIDE 66
__global__ __launch_bounds__(256) void k_gemm2(
    const float* __restrict__ z, const float* __restrict__ W,
    unsigned short* __restrict__ h2h, int n)
{
    __shared__ float Ws[128 * 32];
    __shared__ float zs[128 * ZS_STRIDE];
    int t = threadIdx.x;
    int n0 = blockIdx.x * 64;

    for (int i = t; i < 128 * 8; i += 256) {
        int k = i >> 3, c4 = (i & 7) * 4;
        *(float4*)&Ws[k * 32 + c4] = *(const float4*)&W[k * 32 + c4];
    }
    for (int i = t; i < 64 * 32; i += 256) {
        int nl = i & 63, k4 = (i >> 6) * 4;
        int nn = n0 + nl;
        float4 v = (nn < n) ? *(const float4*)&z[(size_t)nn * 128 + k4]
                            : make_float4(0.f, 0.f, 0.f, 0.f);
        zs[(k4 + 0) * ZS_STRIDE + nl] = v.x;
        zs[(k4 + 1) * ZS_STRIDE + nl] = v.y;
        zs[(k4 + 2) * ZS_STRIDE + nl] = v.z;
        zs[(k4 + 3) * ZS_STRIDE + nl] = v.w;
    }
    __syncthreads();

    int tx = t & 7, ty = t >> 3;
    float acc[2][4] = {};
    #pragma unroll 8
    for (int k = 0; k < 128; ++k) {
        float2 a = *(float2*)&zs[k * ZS_STRIDE + ty * 2];
        float4 b = *(float4*)&Ws[k * 32 + tx * 4];
        float av[2] = {a.x, a.y};
        float bv[4] = {b.x, b.y, b.z, b.w};
        #pragma unroll
        for (int i = 0; i < 2; ++i)
            #pragma unroll
            for (int j = 0; j < 4; ++j)
                acc[i][j] = fmaf(av[i], bv[j], acc[i][j]);
    }
    #pragma unroll
    for (int i = 0; i < 2; ++i) {
        int nn = n0 + ty * 2 + i;
        if (nn < n) {
            ushort4 p;
            p.x = f2h(acc[i][0]); p.y = f2h(acc[i][1]);
            p.z = f2h(acc[i][2]); p.w = f2h(acc[i][3]);
            *(ushort4*)&h2h[(size_t)nn * 32 + tx * 4] = p;
        }
    }
}

// ============ attention coefficient reductions ============
// layer 1: one wave per node; lane covers ch {2l,2l+1}; head = lane>>4
__global__ __launch_bounds__(256) void k_att1(
    const unsigned short* __restrict__ h1h, const float* __restrict__ as_w,
    const float* __restrict__ ad_w, float* __restrict__ as1,
    float* __restrict__ ad1, int n)
{
    int w = threadIdx.x >> 6, lane = threadIdx.x & 63;
    int node = blockIdx.x * 4 + w;
    if (node >= n) return;
    ushort2 u = *(const ushort2*)&h1h[(size_t)node * 128 + 2 * lane];
    float v0 = h2f(u.x), v1 = h2f(u.y);
    float s = v0 * as_w[2 * lane] + v1 * as_w[2 * lane + 1];
    float d = v0 * ad_w[2 * lane] + v1 * ad_w[2 * lane + 1];
    #pragma unroll
    for (int o = 8; o; o >>= 1) { s += __shfl_xor(s, o); d += __shfl_xor(d, o); }
    if ((lane & 15) == 0) {
        int h = lane >> 4;
        as1[(size_t)node * 4 + h] = s;
        ad1[(size_t)node * 4 + h] = d;
    }
}

// layer 2: 16 lanes per node
__global__ __launch_bounds__(256) void k_att2(
    const unsigned short* __restrict__ h2h, const float* __restrict__ as_w,
    const float* __restrict__ ad_w, float* __restrict__ as2,
    float* __restrict__ ad2, int n)
{
    int g = threadIdx.x >> 4, c = threadIdx.x & 15;
    int node = blockIdx.x * 16 + g;
    if (node >= n) return;
    ushort2 u = *(const ushort2*)&h2h[(size_t)node * 32 + 2 * c];
    float v0 = h2f(u.x), v1 = h2f(u.y);
    float s = v0 * as_w[2 * c] + v1 * as_w[2 * c + 1];
    float d = v0 * ad_w[2 * c] + v1 * ad_w[2 * c + 1];
    #pragma unroll
    for (int o = 8; o; o >>= 1) { s += __shfl_xor(s, o); d += __shfl_xor(d, o); }
    if (c == 0) { as2[node] = s; ad2[node] = d; }
}

// ============ fused layer-1 GAT: softmax + fp16 gather + ELU ============
// one wave per dst node; lane covers ch {2l, 2l+1}, head = lane>>4
__global__ __launch_bounds__(256) void k_gat1(
    const int* __restrict__ row_off, const int* __restrict__ csr,
    const float* __restrict__ as1, const float* __restrict__ ad1,
    const unsigned short* __restrict__ h1h, const float* __restrict__ b1,
    float* __restrict__ z, int n)
{
    int w = threadIdx.x >> 6, lane = threadIdx.x & 63;
    int node = blockIdx.x * 4 + w;
    if (node >= n) return;
    __shared__ int   s_src_all[4][CH1];
    __shared__ float s_p_all[4][CH1 * 4];
    int* ssrc = s_src_all[w];
    float* sp = s_p_all[w];

    float add0 = ad1[(size_t)node * 4 + 0];
    float add1 = ad1[(size_t)node * 4 + 1];
    float add2 = ad1[(size_t)node * 4 + 2];
    float add3 = ad1[(size_t)node * 4 + 3];
    int beg = row_off[node], end = row_off[node + 1];
    int h = lane >> 4;

    float mr0 = -1e30f, mr1 = -1e30f, mr2 = -1e30f, mr3 = -1e30f;
    float sr0 = 0.f, sr1 = 0.f, sr2 = 0.f, sr3 = 0.f;
    float acc0 = 0.f, acc1 = 0.f;

    for (int c = beg; c < end; c += CH1) {
        int cnt = min(CH1, end - c);
        float scA0=-1e30f, scA1=-1e30f, scA2=-1e30f, scA3=-1e30f;
        float scB0=-1e30f, scB1=-1e30f, scB2=-1e30f, scB3=-1e30f;
        bool hasA = lane < cnt, hasB = lane + 64 < cnt;
        if (hasA) {
            int sA = csr[c + lane];
            ssrc[lane] = sA;
            float4 av = *(const float4*)&as1[(size_t)sA * 4];
            float v;
            v = av.x + add0; scA0 = v > 0.f ? v : NEG * v;
            v = av.y + add1; scA1 = v > 0.f ? v : NEG * v;
            v = av.z + add2; scA2 = v > 0.f ? v : NEG * v;
            v = av.w + add3; scA3 = v > 0.f ? v : NEG * v;
        }
        if (hasB) {
            int sB = csr[c + lane + 64];
            ssrc[lane + 64] = sB;
            float4 av = *(const float4*)&as1[(size_t)sB * 4];
            float v;
            v = av.x + add0; scB0 = v > 0.f ? v : NEG * v;
            v = av.y + add1; scB1 = v > 0.f ? v : NEG * v;
            v = av.z + add2; scB2 = v > 0.f ? v : NEG * v;
            v = av.w + add3; scB3 = v > 0.f ? v : NEG * v;
        }
        float lm0 = fmaxf(scA0, scB0), lm1 = fmaxf(scA1, scB1);
        float lm2 = fmaxf(scA2, scB2), lm3 = fmaxf(scA3, scB3);
        #pragma unroll
        for (int o = 32; o; o >>= 1) {
            lm0 = fmaxf(lm0, __shfl_xor(lm0, o));
            lm1 = fmaxf(lm1, __shfl_xor(lm1, o));
            lm2 = fmaxf(lm2, __shfl_xor(lm2, o));
            lm3 = fmaxf(lm3, __shfl_xor(lm3, o));
        }
        float nm0 = fmaxf(mr0, lm0), nm1 = fmaxf(mr1, lm1);
        float nm2 = fmaxf(mr2, lm2), nm3 = fmaxf(mr3, lm3);
        // rescale my accumulators (my head's old/new max)
        float om  = h == 0 ? mr0 : h == 1 ? mr1 : h == 2 ? mr2 : mr3;
        float nmh = h == 0 ? nm0 : h == 1 ? nm1 : h == 2 ? nm2 : nm3;
        float r = __expf(om - nmh);
        acc0 *= r; acc1 *= r;
        float ls0 = 0.f, ls1 = 0.f, ls2 = 0.f, ls3 = 0.f;
        if (hasA) {
            float p0 = __expf(scA0 - nm0), p1 = __expf(scA1 - nm1);
            float p2 = __expf(scA2 - nm2), p3 = __expf(scA3 - nm3);
            *(float4*)&sp[lane * 4] = make_float4(p0, p1, p2, p3);
            ls0 += p0; ls1 += p1; ls2 += p2; ls3 += p3;
        }
        if (hasB) {
            float p0 = __expf(scB0 - nm0), p1 = __expf(scB1 - nm1);
            float p2 = __expf(scB2 - nm2), p3 = __expf(scB3 - nm3);
            *(float4*)&sp[(lane + 64) * 4] = make_float4(p0, p1, p2, p3);
            ls0 += p0; ls1 += p1; ls2 += p2; ls3 += p3;
        }
        #pragma unroll
        for (int o = 32; o; o >>= 1) {
            ls0 += __shfl_xor(ls0, o);
            ls1 += __shfl_xor(ls1, o);
            ls2 += __shfl_xor(ls2, o);
            ls3 += __shfl_xor(ls3, o);
        }
        sr0 = sr0 * __expf(mr0 - nm0) + ls0;
        sr1 = sr1 * __expf(mr1 - nm1) + ls1;
        sr2 = sr2 * __expf(mr2 - nm2) + ls2;
        sr3 = sr3 * __expf(mr3 - nm3) + ls3;
        __threadfence_block();
        // ---- fp16 gather: 256 B per edge, lane reads ushort2 ----
        #pragma unroll 4
        for (int j = 0; j < cnt; ++j) {
            int src = ssrc[j];
            float p = sp[j * 4 + h];
            ushort2 u = *(const ushort2*)&h1h[(size_t)src * 128 + 2 * lane];
            acc0 = fmaf(p, h2f(u.x), acc0);
            acc1 = fmaf(p, h2f(u.y), acc1);
        }
        mr0 = nm0; mr1 = nm1; mr2 = nm2; mr3 = nm3;
    }
    float srh = h == 0 ? sr0 : h == 1 ? sr1 : h == 2 ? sr2 : sr3;
    float v0 = acc0 / srh + b1[2 * lane];
    float v1 = acc1 / srh + b1[2 * lane + 1];
    v0 = v0 > 0.f ? v0 : (__expf(v0) - 1.f);
    v1 = v1 > 0.f ? v1 : (__expf(v1) - 1.f);
    *(float2*)&z[(size_t)node * F1 + 2 * lane] = make_float2(v0, v1);
}

// ============ fused layer-2 GAT + log_softmax (fp16 gather) ============
// one wave per dst node; lane = (edge slot eo=lane>>4, ch pair c=lane&15)
__global__ __launch_bounds__(256) void k_gat2(
    const int* __restrict__ row_off, const int* __restrict__ csr,
    const float* __restrict__ as2, const float* __restrict__ ad2,
    const unsigned short* __restrict__ h2h, const float* __restrict__ b2,
    float* __restrict__ y, int n)
{
    int w = threadIdx.x >> 6, lane = threadIdx.x & 63;
    int node = blockIdx.x * 4 + w;
    if (node >= n) return;
    __shared__ int   s_src_all[4][CH2];
    __shared__ float s_p_all[4][CH2];
    int* ssrc = s_src_all[w];
    float* sp = s_p_all[w];

    float addv = ad2[node];
    int beg = row_off[node], end = row_off[node + 1];
    int c2 = lane & 15, eo = lane >> 4;   // 4 edges in flight
    float mr = -1e30f, sr = 0.f, acc0 = 0.f, acc1 = 0.f;

    for (int c = beg; c < end; c += CH2) {
        int cnt = min(CH2, end - c);
        float scA = -1e30f, scB = -1e30f;
        bool hasA = lane < cnt, hasB = lane + 64 < cnt;
        if (hasA) {
            int sA = csr[c + lane];
            ssrc[lane] = sA;
            float v = as2[sA] + addv;
            scA = v > 0.f ? v : NEG * v;
        }
        if (hasB) {
            int sB = csr[c + lane + 64];
            ssrc[lane + 64] = sB;
            float v = as2[sB] + addv;
            scB = v > 0.f ? v : NEG * v;
        }
        float lm = fmaxf(scA, scB);
        #pragma unroll
        for (int o = 32; o; o >>= 1) lm = fmaxf(lm, __shfl_xor(lm, o));
        float nm = fmaxf(mr, lm);
        float r = __expf(mr - nm);
        acc0 *= r; acc1 *= r; sr *= r;
        float ls = 0.f;
        if (hasA) { float p = __expf(scA - nm); sp[lane] = p; ls += p; }
        if (hasB) { float p = __expf(scB - nm); sp[lane + 64] = p; ls += p; }
        #pragma unroll
        for (int o = 32; o; o >>= 1) ls += __shfl_xor(ls, o);
        sr += ls;
        __threadfence_block();
        #pragma unroll 4
        for (int j = eo; j < cnt; j += 4) {
            int src = ssrc[j];
            float p = sp[j];
            ushort2 u = *(const ushort2*)&h2h[(size_t)src * 32 + 2 * c2];
            acc0 = fmaf(p, h2f(u.x), acc0);
            acc1 = fmaf(p, h2f(u.y), acc1);
        }
        mr = nm;
    }
    // fold the 4 edge slots
    acc0 += __shfl_xor(acc0, 16); acc0 += __shfl_xor(acc0, 32);
    acc1 += __shfl_xor(acc1, 16); acc1 += __shfl_xor(acc1, 32);
    float v0 = acc0 / sr + b2[2 * c2];
    float v1 = acc1 / sr + b2[2 * c2 + 1];
    // log_softmax over 32 ch held as 16 lanes x 2 (identical in all eo groups)
    float m = fmaxf(v0, v1);
    #pragma unroll
    for (int o = 8; o; o >>= 1) m = fmaxf(m, __shfl_xor(m, o));
    float ss = __expf(v0 - m) + __expf(v1 - m);
    #pragma unroll
    for (int o = 8; o; o >>= 1) ss += __shfl_xor(ss, o);
    float lg = m + logf(ss);
    if (lane < 16)
        *(float2*)&y[(size_t)node * OUT_C + 2 * c2] = make_float2(v0 - lg, v1 - lg);
}

extern "C" void kernel_launch(void* const* d_in, const int* in_sizes, int n_in,
                              void* d_out, int out_size, void* d_ws, size_t ws_size,
                              hipStream_t stream) {
    const float* x    = (const float*)d_in[0];
    const int*   ei   = (const int*)d_in[1];
    const float* W1   = (const float*)d_in[2];
    const float* as1w = (const float*)d_in[3];
    const float* ad1w = (const float*)d_in[4];
    const float* b1   = (const float*)d_in[5];
    const float* W2   = (const float*)d_in[6];
    const float* as2w = (const float*)d_in[7];
    const float* ad2w = (const float*)d_in[8];
    const float* b2   = (const float*)d_in[9];
    float* out = (float*)d_out;

    int n  = in_sizes[0] / IN_C;
    int E_ = in_sizes[1] / 2;
    int EE = E_ + n;

    char* w = (char*)d_ws;
    size_t off = 0;
    auto take = [&](size_t elems) { void* p = w + off; off += ((elems * 4 + 255) & ~(size_t)255); return p; };
    int* deg     = (int*)take((size_t)n);          // must be zeroed
    int* row_off = (int*)take((size_t)n + 1);
    int* cursor  = (int*)take((size_t)n);
    int* bsum    = (int*)take(1024);
    int* csr     = (int*)take((size_t)EE);
    float* as1   = (float*)take((size_t)n * 4);
    float* ad1   = (float*)take((size_t)n * 4);
    unsigned short* h1h = (unsigned short*)take((size_t)n * 64);  // n*128 fp16
    float* z     = (float*)take((size_t)n * 128);
    unsigned short* h2h = (unsigned short*)take((size_t)n * 16);  // n*32 fp16
    float* as2   = (float*)take((size_t)n);
    float* ad2   = (float*)take((size_t)n);

    hipMemsetAsync(deg, 0, (size_t)n * 4, stream);

    int gE = (EE + 255) / 256;
    int nb = (n + SCAN_B - 1) / SCAN_B;

    // CSR build (shared by both layers)
    k_hist<<<gE, 256, 0, stream>>>(ei, deg, E_, n);
    k_scan1<<<nb, SCAN_B, 0, stream>>>(deg, row_off, bsum, n);
    k_scan2<<<1, 1024, 0, stream>>>(bsum, nb);
    k_scan3<<<(n + 255) / 256, 256, 0, stream>>>(row_off, bsum, cursor, n, EE);
    k_fill<<<gE, 256, 0, stream>>>(ei, cursor, csr, E_, n);

    // layer 1
    int nt = (n + 63) / 64;
    k_gemm1<<<nt * 2, 256, 0, stream>>>(x, W1, h1h, n);
    k_att1<<<(n + 3) / 4, 256, 0, stream>>>(h1h, as1w, ad1w, as1, ad1, n);
    int gG = (n + 3) / 4;
    k_gat1<<<gG, 256, 0, stream>>>(row_off, csr, as1, ad1, h1h, b1, z, n);

    // layer 2
    k_gemm2<<<nt, 256, 0, stream>>>(z, W2, h2h, n);
    k_att2<<<(n + 15) / 16, 256, 0, stream>>>(h2h, as2w, ad2w, as2, ad2, n);
    k_gat2<<<gG, 256, 0, stream>>>(row_off, csr, as2, ad2, h2h, b2, out, n);
}

// Round 6
// 527.931 us; speedup vs baseline: 3.4050x; 1.0387x over previous
//
#include <hip/hip_runtime.h>
#include <hip/hip_fp16.h>
#include <math.h>

#define IN_C   128
#define HEADS  4
#define F1     128   // HEADS*HID
#define OUT_C  32
#define NEG    0.2f
#define CH1    128   // edge chunk per node-wave (layer 1)
#define CH2    128
#define SH     8     // bucket = dst >> SH (256 dsts per bucket); needs n <= 2^17
#define CHA    8192  // edges per chunk in CSR pass A

// ---- fp16 helpers (RNE) ----
__device__ __forceinline__ unsigned short f2h(float f) {
    return __half_as_ushort(__float2half_rn(f));
}
__device__ __forceinline__ float h2f(unsigned short u) {
    return __half2float(__ushort_as_half(u));
}

// ============ CSR pass A1: per-chunk bucket histogram (LDS atomics only) ======
__global__ __launch_bounds__(256) void k_bhist(
    const int* __restrict__ ei, int* __restrict__ bmat, int E_, int n, int NB, int NC)
{
    __shared__ int h[512];
    int t = threadIdx.x, c = blockIdx.x;
    for (int i = t; i < NB; i += 256) h[i] = 0;
    __syncthreads();
    int e0 = c * CHA, e1 = min(e0 + CHA, E_ + n);
    for (int e = e0 + t; e < e1; e += 256) {
        int d = (e < E_) ? ei[E_ + e] : e - E_;
        atomicAdd(&h[d >> SH], 1);
    }
    __syncthreads();
    for (int i = t; i < NB; i += 256) bmat[i * NC + c] = h[i];
}

// ============ CSR pass A2: exclusive scan of bmat (bucket-major), one block ===
__global__ __launch_bounds__(1024) void k_bscan(int* __restrict__ bmat, int M, int per)
{
    __shared__ int tot[1024];
    int t = threadIdx.x;
    int i0 = t * per, i1 = min(i0 + per, M);
    int s = 0;
    for (int i = i0; i < i1; ++i) s += bmat[i];
    tot[t] = s;
    __syncthreads();
    for (int off = 1; off < 1024; off <<= 1) {
        int a = (t >= off) ? tot[t - off] : 0;
        __syncthreads();
        tot[t] += a;
        __syncthreads();
    }
    int base = tot[t] - s;   // exclusive over thread ranges
    for (int i = i0; i < i1; ++i) { int v = bmat[i]; bmat[i] = base; base += v; }
}

// ============ CSR pass A3: scatter packed recs into (bucket,chunk) ranges =====
__global__ __launch_bounds__(256) void k_bscatter(
    const int* __restrict__ ei, const int* __restrict__ bmat,
    unsigned* __restrict__ recs, int E_, int n, int NB, int NC)
{
    __shared__ int cur[512];
    int t = threadIdx.x, c = blockIdx.x;
    for (int i = t; i < NB; i += 256) cur[i] = bmat[i * NC + c];
    __syncthreads();
    int e0 = c * CHA, e1 = min(e0 + CHA, E_ + n);
    for (int e = e0 + t; e < e1; e += 256) {
        int s, d;
        if (e < E_) { s = ei[e]; d = ei[E_ + e]; } else { s = d = e - E_; }
        int b = d >> SH;
        int p = atomicAdd(&cur[b], 1);   // LDS atomic
        recs[p] = ((unsigned)(d & ((1 << SH) - 1)) << 17) | (unsigned)s;
    }
}

// ============ CSR pass B: per-bucket fine fill (one block owns one bucket) ====
__global__ __launch_bounds__(256) void k_bfill(
    const unsigned* __restrict__ recs, const int* __restrict__ bmat,
    int* __restrict__ row_off, int* __restrict__ csr, int n, int NB, int NC, int EE)
{
    __shared__ int deg[256];
    __shared__ int cur[256];
    int t = threadIdx.x, b = blockIdx.x;
    int r0 = bmat[b * NC];
    int r1 = (b + 1 < NB) ? bmat[(b + 1) * NC] : EE;
    deg[t] = 0;
    __syncthreads();
    for (int i = r0 + t; i < r1; i += 256)
        atomicAdd(&deg[recs[i] >> 17], 1);
    __syncthreads();
    int v = deg[t];
    for (int off = 1; off < 256; off <<= 1) {
        int a = (t >= off) ? deg[t - off] : 0;
        __syncthreads();
        deg[t] += a;
        __syncthreads();
    }
    int excl = deg[t] - v;
    int dst = (b << SH) + t;
    if (dst < n) row_off[dst] = r0 + excl;
    cur[t] = excl;
    if (b == NB - 1 && t == 0) row_off[n] = EE;
    __syncthreads();
    for (int i = r0 + t; i < r1; i += 256) {
        unsigned rec = recs[i];
        int dl = rec >> 17;
        int p = atomicAdd(&cur[dl], 1);   // LDS atomic
        csr[r0 + p] = (int)(rec & 0x1FFFFu);
    }
}

// ============ layer-1 GEMM: h1 = x@W1 (fp16 out), register-tiled ============
#define XS_STRIDE 68
__global__ __launch_bounds__(256) void k_gemm1(
    const float* __restrict__ x, const float* __restrict__ W,
    unsigned short* __restrict__ h1h, int n)
{
    __shared__ float Ws[128 * 64];
    __shared__ float xs[128 * XS_STRIDE];
    int t = threadIdx.x;
    int half = blockIdx.x & 1;
    int n0 = (blockIdx.x >> 1) * 64;

    for (int i = t; i < 128 * 16; i += 256) {
        int k = i >> 4, c4 = (i & 15) * 4;
        *(float4*)&Ws[k * 64 + c4] = *(const float4*)&W[k * 128 + half * 64 + c4];
    }
    for (int i = t; i < 64 * 32; i += 256) {
        int nl = i & 63, k4 = (i >> 6) * 4;
        int nn = n0 + nl;
        float4 v = (nn < n) ? *(const float4*)&x[(size_t)nn * 128 + k4]
                            : make_float4(0.f, 0.f, 0.f, 0.f);
        xs[(k4 + 0) * XS_STRIDE + nl] = v.x;
        xs[(k4 + 1) * XS_STRIDE + nl] = v.y;
        xs[(k4 + 2) * XS_STRIDE + nl] = v.z;
        xs[(k4 + 3) * XS_STRIDE + nl] = v.w;
    }
    __syncthreads();

    int tx = t & 15, ty = t >> 4;
    float acc[4][4] = {};
    #pragma unroll 8
    for (int k = 0; k < 128; ++k) {
        float4 a = *(float4*)&xs[k * XS_STRIDE + ty * 4];
        float4 b = *(float4*)&Ws[k * 64 + tx * 4];
        float av[4] = {a.x, a.y, a.z, a.w};
        float bv[4] = {b.x, b.y, b.z, b.w};
        #pragma unroll
        for (int i = 0; i < 4; ++i)
            #pragma unroll
            for (int j = 0; j < 4; ++j)
                acc[i][j] = fmaf(av[i], bv[j], acc[i][j]);
    }
    int cbase = half * 64 + tx * 4;
    #pragma unroll
    for (int i = 0; i < 4; ++i) {
        int nn = n0 + ty * 4 + i;
        if (nn < n) {
            ushort4 p;
            p.x = f2h(acc[i][0]); p.y = f2h(acc[i][1]);
            p.z = f2h(acc[i][2]); p.w = f2h(acc[i][3]);
            *(ushort4*)&h1h[(size_t)nn * 128 + cbase] = p;
        }
    }
}

// ============ layer-2 GEMM: h2 = z@W2 (fp16 out) ============
#define ZS_STRIDE 66
__global__ __launch_bounds__(256) void k_gemm2(
    const float* __restrict__ z, const float* __restrict__ W,
    unsigned short* __restrict__ h2h, int n)
{
    __shared__ float Ws[128 * 32];
    __shared__ float zs[128 * ZS_STRIDE];
    int t = threadIdx.x;
    int n0 = blockIdx.x * 64;

    for (int i = t; i < 128 * 8; i += 256) {
        int k = i >> 3, c4 = (i & 7) * 4;
        *(float4*)&Ws[k * 32 + c4] = *(const float4*)&W[k * 32 + c4];
    }
    for (int i = t; i < 64 * 32; i += 256) {
        int nl = i & 63, k4 = (i >> 6) * 4;
        int nn = n0 + nl;
        float4 v = (nn < n) ? *(const float4*)&z[(size_t)nn * 128 + k4]
                            : make_float4(0.f, 0.f, 0.f, 0.f);
        zs[(k4 + 0) * ZS_STRIDE + nl] = v.x;
        zs[(k4 + 1) * ZS_STRIDE + nl] = v.y;
        zs[(k4 + 2) * ZS_STRIDE + nl] = v.z;
        zs[(k4 + 3) * ZS_STRIDE + nl] = v.w;
    }
    __syncthreads();

    int tx = t & 7, ty = t >> 3;
    float acc[2][4] = {};
    #pragma unroll 8
    for (int k = 0; k < 128; ++k) {
        float2 a = *(float2*)&zs[k * ZS_STRIDE + ty * 2];
        float4 b = *(float4*)&Ws[k * 32 + tx * 4];
        float av[2] = {a.x, a.y};
        float bv[4] = {b.x, b.y, b.z, b.w};
        #pragma unroll
        for (int i = 0; i < 2; ++i)
            #pragma unroll
            for (int j = 0; j < 4; ++j)
                acc[i][j] = fmaf(av[i], bv[j], acc[i][j]);
    }
    #pragma unroll
    for (int i = 0; i < 2; ++i) {
        int nn = n0 + ty * 2 + i;
        if (nn < n) {
            ushort4 p;
            p.x = f2h(acc[i][0]); p.y = f2h(acc[i][1]);
            p.z = f2h(acc[i][2]); p.w = f2h(acc[i][3]);
            *(ushort4*)&h2h[(size_t)nn * 32 + tx * 4] = p;
        }
    }
}

// ============ attention coefficient reductions ============
__global__ __launch_bounds__(256) void k_att1(
    const unsigned short* __restrict__ h1h, const float* __restrict__ as_w,
    const float* __restrict__ ad_w, float* __restrict__ as1,
    float* __restrict__ ad1, int n)
{
    int w = threadIdx.x >> 6, lane = threadIdx.x & 63;
    int node = blockIdx.x * 4 + w;
    if (node >= n) return;
    ushort2 u = *(const ushort2*)&h1h[(size_t)node * 128 + 2 * lane];
    float v0 = h2f(u.x), v1 = h2f(u.y);
    float s = v0 * as_w[2 * lane] + v1 * as_w[2 * lane + 1];
    float d = v0 * ad_w[2 * lane] + v1 * ad_w[2 * lane + 1];
    #pragma unroll
    for (int o = 8; o; o >>= 1) { s += __shfl_xor(s, o); d += __shfl_xor(d, o); }
    if ((lane & 15) == 0) {
        int h = lane >> 4;
        as1[(size_t)node * 4 + h] = s;
        ad1[(size_t)node * 4 + h] = d;
    }
}

__global__ __launch_bounds__(256) void k_att2(
    const unsigned short* __restrict__ h2h, const float* __restrict__ as_w,
    const float* __restrict__ ad_w, float* __restrict__ as2,
    float* __restrict__ ad2, int n)
{
    int g = threadIdx.x >> 4, c = threadIdx.x & 15;
    int node = blockIdx.x * 16 + g;
    if (node >= n) return;
    ushort2 u = *(const ushort2*)&h2h[(size_t)node * 32 + 2 * c];
    float v0 = h2f(u.x), v1 = h2f(u.y);
    float s = v0 * as_w[2 * c] + v1 * as_w[2 * c + 1];
    float d = v0 * ad_w[2 * c] + v1 * ad_w[2 * c + 1];
    #pragma unroll
    for (int o = 8; o; o >>= 1) { s += __shfl_xor(s, o); d += __shfl_xor(d, o); }
    if (c == 0) { as2[node] = s; ad2[node] = d; }
}

// ============ fused layer-1 GAT: softmax + fp16 gather + ELU ============
__global__ __launch_bounds__(256) void k_gat1(
    const int* __restrict__ row_off, const int* __restrict__ csr,
    const float* __restrict__ as1, const float* __restrict__ ad1,
    const unsigned short* __restrict__ h1h, const float* __restrict__ b1,
    float* __restrict__ z, int n)
{
    int w = threadIdx.x >> 6, lane = threadIdx.x & 63;
    int node = blockIdx.x * 4 + w;
    if (node >= n) return;
    __shared__ int   s_src_all[4][CH1];
    __shared__ float s_p_all[4][CH1 * 4];
    int* ssrc = s_src_all[w];
    float* sp = s_p_all[w];

    float add0 = ad1[(size_t)node * 4 + 0];
    float add1 = ad1[(size_t)node * 4 + 1];
    float add2 = ad1[(size_t)node * 4 + 2];
    float add3 = ad1[(size_t)node * 4 + 3];
    int beg = row_off[node], end = row_off[node + 1];
    int h = lane >> 4;

    float mr0 = -1e30f, mr1 = -1e30f, mr2 = -1e30f, mr3 = -1e30f;
    float sr0 = 0.f, sr1 = 0.f, sr2 = 0.f, sr3 = 0.f;
    float acc0 = 0.f, acc1 = 0.f;

    for (int c = beg; c < end; c += CH1) {
        int cnt = min(CH1, end - c);
        float scA0=-1e30f, scA1=-1e30f, scA2=-1e30f, scA3=-1e30f;
        float scB0=-1e30f, scB1=-1e30f, scB2=-1e30f, scB3=-1e30f;
        bool hasA = lane < cnt, hasB = lane + 64 < cnt;
        if (hasA) {
            int sA = csr[c + lane];
            ssrc[lane] = sA;
            float4 av = *(const float4*)&as1[(size_t)sA * 4];
            float v;
            v = av.x + add0; scA0 = v > 0.f ? v : NEG * v;
            v = av.y + add1; scA1 = v > 0.f ? v : NEG * v;
            v = av.z + add2; scA2 = v > 0.f ? v : NEG * v;
            v = av.w + add3; scA3 = v > 0.f ? v : NEG * v;
        }
        if (hasB) {
            int sB = csr[c + lane + 64];
            ssrc[lane + 64] = sB;
            float4 av = *(const float4*)&as1[(size_t)sB * 4];
            float v;
            v = av.x + add0; scB0 = v > 0.f ? v : NEG * v;
            v = av.y + add1; scB1 = v > 0.f ? v : NEG * v;
            v = av.z + add2; scB2 = v > 0.f ? v : NEG * v;
            v = av.w + add3; scB3 = v > 0.f ? v : NEG * v;
        }
        float lm0 = fmaxf(scA0, scB0), lm1 = fmaxf(scA1, scB1);
        float lm2 = fmaxf(scA2, scB2), lm3 = fmaxf(scA3, scB3);
        #pragma unroll
        for (int o = 32; o; o >>= 1) {
            lm0 = fmaxf(lm0, __shfl_xor(lm0, o));
            lm1 = fmaxf(lm1, __shfl_xor(lm1, o));
            lm2 = fmaxf(lm2, __shfl_xor(lm2, o));
            lm3 = fmaxf(lm3, __shfl_xor(lm3, o));
        }
        float nm0 = fmaxf(mr0, lm0), nm1 = fmaxf(mr1, lm1);
        float nm2 = fmaxf(mr2, lm2), nm3 = fmaxf(mr3, lm3);
        float om  = h == 0 ? mr0 : h == 1 ? mr1 : h == 2 ? mr2 : mr3;
        float nmh = h == 0 ? nm0 : h == 1 ? nm1 : h == 2 ? nm2 : nm3;
        float r = __expf(om - nmh);
        acc0 *= r; acc1 *= r;
        float ls0 = 0.f, ls1 = 0.f, ls2 = 0.f, ls3 = 0.f;
        if (hasA) {
            float p0 = __expf(scA0 - nm0), p1 = __expf(scA1 - nm1);
            float p2 = __expf(scA2 - nm2), p3 = __expf(scA3 - nm3);
            *(float4*)&sp[lane * 4] = make_float4(p0, p1, p2, p3);
            ls0 += p0; ls1 += p1; ls2 += p2; ls3 += p3;
        }
        if (hasB) {
            float p0 = __expf(scB0 - nm0), p1 = __expf(scB1 - nm1);
            float p2 = __expf(scB2 - nm2), p3 = __expf(scB3 - nm3);
            *(float4*)&sp[(lane + 64) * 4] = make_float4(p0, p1, p2, p3);
            ls0 += p0; ls1 += p1; ls2 += p2; ls3 += p3;
        }
        #pragma unroll
        for (int o = 32; o; o >>= 1) {
            ls0 += __shfl_xor(ls0, o);
            ls1 += __shfl_xor(ls1, o);
            ls2 += __shfl_xor(ls2, o);
            ls3 += __shfl_xor(ls3, o);
        }
        sr0 = sr0 * __expf(mr0 - nm0) + ls0;
        sr1 = sr1 * __expf(mr1 - nm1) + ls1;
        sr2 = sr2 * __expf(mr2 - nm2) + ls2;
        sr3 = sr3 * __expf(mr3 - nm3) + ls3;
        __threadfence_block();
        #pragma unroll 4
        for (int j = 0; j < cnt; ++j) {
            int src = ssrc[j];
            float p = sp[j * 4 + h];
            ushort2 u = *(const ushort2*)&h1h[(size_t)src * 128 + 2 * lane];
            acc0 = fmaf(p, h2f(u.x), acc0);
            acc1 = fmaf(p, h2f(u.y), acc1);
        }
        mr0 = nm0; mr1 = nm1; mr2 = nm2; mr3 = nm3;
    }
    float srh = h == 0 ? sr0 : h == 1 ? sr1 : h == 2 ? sr2 : sr3;
    float v0 = acc0 / srh + b1[2 * lane];
    float v1 = acc1 / srh + b1[2 * lane + 1];
    v0 = v0 > 0.f ? v0 : (__expf(v0) - 1.f);
    v1 = v1 > 0.f ? v1 : (__expf(v1) - 1.f);
    *(float2*)&z[(size_t)node * F1 + 2 * lane] = make_float2(v0, v1);
}

// ============ fused layer-2 GAT + log_softmax (fp16 gather) ============
__global__ __launch_bounds__(256) void k_gat2(
    const int* __restrict__ row_off, const int* __restrict__ csr,
    const float* __restrict__ as2, const float* __restrict__ ad2,
    const unsigned short* __restrict__ h2h, const float* __restrict__ b2,
    float* __restrict__ y, int n)
{
    int w = threadIdx.x >> 6, lane = threadIdx.x & 63;
    int node = blockIdx.x * 4 + w;
    if (node >= n) return;
    __shared__ int   s_src_all[4][CH2];
    __shared__ float s_p_all[4][CH2];
    int* ssrc = s_src_all[w];
    float* sp = s_p_all[w];

    float addv = ad2[node];
    int beg = row_off[node], end = row_off[node + 1];
    int c2 = lane & 15, eo = lane >> 4;   // 4 edges in flight
    float mr = -1e30f, sr = 0.f, acc0 = 0.f, acc1 = 0.f;

    for (int c = beg; c < end; c += CH2) {
        int cnt = min(CH2, end - c);
        float scA = -1e30f, scB = -1e30f;
        bool hasA = lane < cnt, hasB = lane + 64 < cnt;
        if (hasA) {
            int sA = csr[c + lane];
            ssrc[lane] = sA;
            float v = as2[sA] + addv;
            scA = v > 0.f ? v : NEG * v;
        }
        if (hasB) {
            int sB = csr[c + lane + 64];
            ssrc[lane + 64] = sB;
            float v = as2[sB] + addv;
            scB = v > 0.f ? v : NEG * v;
        }
        float lm = fmaxf(scA, scB);
        #pragma unroll
        for (int o = 32; o; o >>= 1) lm = fmaxf(lm, __shfl_xor(lm, o));
        float nm = fmaxf(mr, lm);
        float r = __expf(mr - nm);
        acc0 *= r; acc1 *= r; sr *= r;
        float ls = 0.f;
        if (hasA) { float p = __expf(scA - nm); sp[lane] = p; ls += p; }
        if (hasB) { float p = __expf(scB - nm); sp[lane + 64] = p; ls += p; }
        #pragma unroll
        for (int o = 32; o; o >>= 1) ls += __shfl_xor(ls, o);
        sr += ls;
        __threadfence_block();
        #pragma unroll 4
        for (int j = eo; j < cnt; j += 4) {
            int src = ssrc[j];
            float p = sp[j];
            ushort2 u = *(const ushort2*)&h2h[(size_t)src * 32 + 2 * c2];
            acc0 = fmaf(p, h2f(u.x), acc0);
            acc1 = fmaf(p, h2f(u.y), acc1);
        }
        mr = nm;
    }
    acc0 += __shfl_xor(acc0, 16); acc0 += __shfl_xor(acc0, 32);
    acc1 += __shfl_xor(acc1, 16); acc1 += __shfl_xor(acc1, 32);
    float v0 = acc0 / sr + b2[2 * c2];
    float v1 = acc1 / sr + b2[2 * c2 + 1];
    float m = fmaxf(v0, v1);
    #pragma unroll
    for (int o = 8; o; o >>= 1) m = fmaxf(m, __shfl_xor(m, o));
    float ss = __expf(v0 - m) + __expf(v1 - m);
    #pragma unroll
    for (int o = 8; o; o >>= 1) ss += __shfl_xor(ss, o);
    float lg = m + logf(ss);
    if (lane < 16)
        *(float2*)&y[(size_t)node * OUT_C + 2 * c2] = make_float2(v0 - lg, v1 - lg);
}

extern "C" void kernel_launch(void* const* d_in, const int* in_sizes, int n_in,
                              void* d_out, int out_size, void* d_ws, size_t ws_size,
                              hipStream_t stream) {
    const float* x    = (const float*)d_in[0];
    const int*   ei   = (const int*)d_in[1];
    const float* W1   = (const float*)d_in[2];
    const float* as1w = (const float*)d_in[3];
    const float* ad1w = (const float*)d_in[4];
    const float* b1   = (const float*)d_in[5];
    const float* W2   = (const float*)d_in[6];
    const float* as2w = (const float*)d_in[7];
    const float* ad2w = (const float*)d_in[8];
    const float* b2   = (const float*)d_in[9];
    float* out = (float*)d_out;

    int n  = in_sizes[0] / IN_C;
    int E_ = in_sizes[1] / 2;
    int EE = E_ + n;

    int NB = (n + (1 << SH) - 1) >> SH;        // buckets (<=512 for n<=131072)
    int NC = (EE + CHA - 1) / CHA;             // chunks
    int M  = NB * NC;
    int per = (M + 1023) / 1024;

    char* w = (char*)d_ws;
    size_t off = 0;
    auto take = [&](size_t elems) { void* p = w + off; off += ((elems * 4 + 255) & ~(size_t)255); return p; };
    int* bmat      = (int*)take((size_t)M);
    unsigned* recs = (unsigned*)take((size_t)EE);
    int* row_off   = (int*)take((size_t)n + 1);
    int* csr       = (int*)take((size_t)EE);
    float* as1     = (float*)take((size_t)n * 4);
    float* ad1     = (float*)take((size_t)n * 4);
    unsigned short* h1h = (unsigned short*)take((size_t)n * 64);  // n*128 fp16
    float* z       = (float*)take((size_t)n * 128);
    unsigned short* h2h = (unsigned short*)take((size_t)n * 16);  // n*32 fp16
    float* as2     = (float*)take((size_t)n);
    float* ad2     = (float*)take((size_t)n);

    // CSR build: bucketed counting sort, no global atomics
    k_bhist   <<<NC, 256, 0, stream>>>(ei, bmat, E_, n, NB, NC);
    k_bscan   <<<1, 1024, 0, stream>>>(bmat, M, per);
    k_bscatter<<<NC, 256, 0, stream>>>(ei, bmat, recs, E_, n, NB, NC);
    k_bfill   <<<NB, 256, 0, stream>>>(recs, bmat, row_off, csr, n, NB, NC, EE);

    // layer 1
    int nt = (n + 63) / 64;
    k_gemm1<<<nt * 2, 256, 0, stream>>>(x, W1, h1h, n);
    k_att1<<<(n + 3) / 4, 256, 0, stream>>>(h1h, as1w, ad1w, as1, ad1, n);
    int gG = (n + 3) / 4;
    k_gat1<<<gG, 256, 0, stream>>>(row_off, csr, as1, ad1, h1h, b1, z, n);

    // layer 2
    k_gemm2<<<nt, 256, 0, stream>>>(z, W2, h2h, n);
    k_att2<<<(n + 15) / 16, 256, 0, stream>>>(h2h, as2w, ad2w, as2, ad2, n);
    k_gat2<<<gG, 256, 0, stream>>>(row_off, csr, as2, ad2, h2h, b2, out, n);
}

// Round 7
// 402.961 us; speedup vs baseline: 4.4610x; 1.3101x over previous
//
#include <hip/hip_runtime.h>
#include <hip/hip_fp16.h>
#include <math.h>

#define IN_C   128
#define HEADS  4
#define F1     128   // HEADS*HID
#define OUT_C  32
#define NEG    0.2f
#define CH1    128   // edge chunk per node-wave (layer 1)
#define CH2    128
#define SH     8     // bucket = dst >> SH (256 dsts per bucket); needs n <= 2^17
#define CHA    8192  // edges per chunk in CSR pass A
#define SCB    4096  // elements per scan block (256 thr x 16)

// ---- fp16 helpers (RNE) ----
__device__ __forceinline__ unsigned short f2h(float f) {
    return __half_as_ushort(__float2half_rn(f));
}
__device__ __forceinline__ float h2f(unsigned short u) {
    return __half2float(__ushort_as_half(u));
}

// ============ CSR pass A1: per-chunk bucket histogram (LDS atomics only) ======
__global__ __launch_bounds__(256) void k_bhist(
    const int* __restrict__ ei, int* __restrict__ bmat, int E_, int n, int NB, int NC)
{
    __shared__ int h[512];
    int t = threadIdx.x, c = blockIdx.x;
    for (int i = t; i < NB; i += 256) h[i] = 0;
    __syncthreads();
    int e0 = c * CHA, e1 = min(e0 + CHA, E_ + n);
    for (int e = e0 + t; e < e1; e += 256) {
        int d = (e < E_) ? ei[E_ + e] : e - E_;
        atomicAdd(&h[d >> SH], 1);
    }
    __syncthreads();
    for (int i = t; i < NB; i += 256) bmat[i * NC + c] = h[i];
}

// ============ CSR pass A2: parallel exclusive scan of bmat (3 stages) ========
__global__ __launch_bounds__(256) void k_scanA(
    int* __restrict__ bmat, int* __restrict__ bsums, int M)
{
    __shared__ int sm[256];
    int t = threadIdx.x;
    int base = blockIdx.x * SCB + t * 16;
    int v[16];
    int s = 0;
    #pragma unroll
    for (int j = 0; j < 16; ++j) {
        int i = base + j;
        v[j] = (i < M) ? bmat[i] : 0;
        s += v[j];
    }
    sm[t] = s;
    __syncthreads();
    for (int off = 1; off < 256; off <<= 1) {
        int a = (t >= off) ? sm[t - off] : 0;
        __syncthreads();
        sm[t] += a;
        __syncthreads();
    }
    int excl = sm[t] - s;
    #pragma unroll
    for (int j = 0; j < 16; ++j) {
        int i = base + j;
        if (i < M) bmat[i] = excl;
        excl += v[j];
    }
    if (t == 255) bsums[blockIdx.x] = sm[255];
}

__global__ __launch_bounds__(256) void k_scanB(int* __restrict__ bsums, int NBLK)
{
    __shared__ int sm[256];
    int t = threadIdx.x;
    int v = (t < NBLK) ? bsums[t] : 0;
    sm[t] = v;
    __syncthreads();
    for (int off = 1; off < 256; off <<= 1) {
        int a = (t >= off) ? sm[t - off] : 0;
        __syncthreads();
        sm[t] += a;
        __syncthreads();
    }
    if (t < NBLK) bsums[t] = sm[t] - v;
}

__global__ __launch_bounds__(256) void k_scanC(
    int* __restrict__ bmat, const int* __restrict__ bsums, int M)
{
    int i = blockIdx.x * 256 + threadIdx.x;
    if (i < M) bmat[i] += bsums[i >> 12];   // 4096 = 1<<12
}

// ============ CSR pass A3: scatter packed recs into (bucket,chunk) ranges =====
__global__ __launch_bounds__(256) void k_bscatter(
    const int* __restrict__ ei, const int* __restrict__ bmat,
    unsigned* __restrict__ recs, int E_, int n, int NB, int NC)
{
    __shared__ int cur[512];
    int t = threadIdx.x, c = blockIdx.x;
    for (int i = t; i < NB; i += 256) cur[i] = bmat[i * NC + c];
    __syncthreads();
    int e0 = c * CHA, e1 = min(e0 + CHA, E_ + n);
    for (int e = e0 + t; e < e1; e += 256) {
        int s, d;
        if (e < E_) { s = ei[e]; d = ei[E_ + e]; } else { s = d = e - E_; }
        int b = d >> SH;
        int p = atomicAdd(&cur[b], 1);   // LDS atomic
        recs[p] = ((unsigned)(d & ((1 << SH) - 1)) << 17) | (unsigned)s;
    }
}

// ============ CSR pass B: per-bucket fine fill (one block owns one bucket) ====
__global__ __launch_bounds__(256) void k_bfill(
    const unsigned* __restrict__ recs, const int* __restrict__ bmat,
    int* __restrict__ row_off, int* __restrict__ csr, int n, int NB, int NC, int EE)
{
    __shared__ int deg[256];
    __shared__ int cur[256];
    int t = threadIdx.x, b = blockIdx.x;
    int r0 = bmat[b * NC];
    int r1 = (b + 1 < NB) ? bmat[(b + 1) * NC] : EE;
    deg[t] = 0;
    __syncthreads();
    for (int i = r0 + t; i < r1; i += 256)
        atomicAdd(&deg[recs[i] >> 17], 1);
    __syncthreads();
    int v = deg[t];
    for (int off = 1; off < 256; off <<= 1) {
        int a = (t >= off) ? deg[t - off] : 0;
        __syncthreads();
        deg[t] += a;
        __syncthreads();
    }
    int excl = deg[t] - v;
    int dst = (b << SH) + t;
    if (dst < n) row_off[dst] = r0 + excl;
    cur[t] = excl;
    if (b == NB - 1 && t == 0) row_off[n] = EE;
    __syncthreads();
    for (int i = r0 + t; i < r1; i += 256) {
        unsigned rec = recs[i];
        int dl = rec >> 17;
        int p = atomicAdd(&cur[dl], 1);   // LDS atomic
        csr[r0 + p] = (int)(rec & 0x1FFFFu);
    }
}

// ============ layer-1 GEMM: h1 = x@W1 (fp16 out), register-tiled ============
#define XS_STRIDE 68
__global__ __launch_bounds__(256) void k_gemm1(
    const float* __restrict__ x, const float* __restrict__ W,
    unsigned short* __restrict__ h1h, int n)
{
    __shared__ float Ws[128 * 64];
    __shared__ float xs[128 * XS_STRIDE];
    int t = threadIdx.x;
    int half = blockIdx.x & 1;
    int n0 = (blockIdx.x >> 1) * 64;

    for (int i = t; i < 128 * 16; i += 256) {
        int k = i >> 4, c4 = (i & 15) * 4;
        *(float4*)&Ws[k * 64 + c4] = *(const float4*)&W[k * 128 + half * 64 + c4];
    }
    for (int i = t; i < 64 * 32; i += 256) {
        int nl = i & 63, k4 = (i >> 6) * 4;
        int nn = n0 + nl;
        float4 v = (nn < n) ? *(const float4*)&x[(size_t)nn * 128 + k4]
                            : make_float4(0.f, 0.f, 0.f, 0.f);
        xs[(k4 + 0) * XS_STRIDE + nl] = v.x;
        xs[(k4 + 1) * XS_STRIDE + nl] = v.y;
        xs[(k4 + 2) * XS_STRIDE + nl] = v.z;
        xs[(k4 + 3) * XS_STRIDE + nl] = v.w;
    }
    __syncthreads();

    int tx = t & 15, ty = t >> 4;
    float acc[4][4] = {};
    #pragma unroll 8
    for (int k = 0; k < 128; ++k) {
        float4 a = *(float4*)&xs[k * XS_STRIDE + ty * 4];
        float4 b = *(float4*)&Ws[k * 64 + tx * 4];
        float av[4] = {a.x, a.y, a.z, a.w};
        float bv[4] = {b.x, b.y, b.z, b.w};
        #pragma unroll
        for (int i = 0; i < 4; ++i)
            #pragma unroll
            for (int j = 0; j < 4; ++j)
                acc[i][j] = fmaf(av[i], bv[j], acc[i][j]);
    }
    int cbase = half * 64 + tx * 4;
    #pragma unroll
    for (int i = 0; i < 4; ++i) {
        int nn = n0 + ty * 4 + i;
        if (nn < n) {
            ushort4 p;
            p.x = f2h(acc[i][0]); p.y = f2h(acc[i][1]);
            p.z = f2h(acc[i][2]); p.w = f2h(acc[i][3]);
            *(ushort4*)&h1h[(size_t)nn * 128 + cbase] = p;
        }
    }
}

// ============ layer-2 GEMM: h2 = z@W2 (fp16 out) ============
#define ZS_STRIDE 66
__global__ __launch_bounds__(256) void k_gemm2(
    const float* __restrict__ z, const float* __restrict__ W,
    unsigned short* __restrict__ h2h, int n)
{
    __shared__ float Ws[128 * 32];
    __shared__ float zs[128 * ZS_STRIDE];
    int t = threadIdx.x;
    int n0 = blockIdx.x * 64;

    for (int i = t; i < 128 * 8; i += 256) {
        int k = i >> 3, c4 = (i & 7) * 4;
        *(float4*)&Ws[k * 32 + c4] = *(const float4*)&W[k * 32 + c4];
    }
    for (int i = t; i < 64 * 32; i += 256) {
        int nl = i & 63, k4 = (i >> 6) * 4;
        int nn = n0 + nl;
        float4 v = (nn < n) ? *(const float4*)&z[(size_t)nn * 128 + k4]
                            : make_float4(0.f, 0.f, 0.f, 0.f);
        zs[(k4 + 0) * ZS_STRIDE + nl] = v.x;
        zs[(k4 + 1) * ZS_STRIDE + nl] = v.y;
        zs[(k4 + 2) * ZS_STRIDE + nl] = v.z;
        zs[(k4 + 3) * ZS_STRIDE + nl] = v.w;
    }
    __syncthreads();

    int tx = t & 7, ty = t >> 3;
    float acc[2][4] = {};
    #pragma unroll 8
    for (int k = 0; k < 128; ++k) {
        float2 a = *(float2*)&zs[k * ZS_STRIDE + ty * 2];
        float4 b = *(float4*)&Ws[k * 32 + tx * 4];
        float av[2] = {a.x, a.y};
        float bv[4] = {b.x, b.y, b.z, b.w};
        #pragma unroll
        for (int i = 0; i < 2; ++i)
            #pragma unroll
            for (int j = 0; j < 4; ++j)
                acc[i][j] = fmaf(av[i], bv[j], acc[i][j]);
    }
    #pragma unroll
    for (int i = 0; i < 2; ++i) {
        int nn = n0 + ty * 2 + i;
        if (nn < n) {
            ushort4 p;
            p.x = f2h(acc[i][0]); p.y = f2h(acc[i][1]);
            p.z = f2h(acc[i][2]); p.w = f2h(acc[i][3]);
            *(ushort4*)&h2h[(size_t)nn * 32 + tx * 4] = p;
        }
    }
}

// ============ attention coefficient reductions ============
__global__ __launch_bounds__(256) void k_att1(
    const unsigned short* __restrict__ h1h, const float* __restrict__ as_w,
    const float* __restrict__ ad_w, float* __restrict__ as1,
    float* __restrict__ ad1, int n)
{
    int w = threadIdx.x >> 6, lane = threadIdx.x & 63;
    int node = blockIdx.x * 4 + w;
    if (node >= n) return;
    ushort2 u = *(const ushort2*)&h1h[(size_t)node * 128 + 2 * lane];
    float v0 = h2f(u.x), v1 = h2f(u.y);
    float s = v0 * as_w[2 * lane] + v1 * as_w[2 * lane + 1];
    float d = v0 * ad_w[2 * lane] + v1 * ad_w[2 * lane + 1];
    #pragma unroll
    for (int o = 8; o; o >>= 1) { s += __shfl_xor(s, o); d += __shfl_xor(d, o); }
    if ((lane & 15) == 0) {
        int h = lane >> 4;
        as1[(size_t)node * 4 + h] = s;
        ad1[(size_t)node * 4 + h] = d;
    }
}

__global__ __launch_bounds__(256) void k_att2(
    const unsigned short* __restrict__ h2h, const float* __restrict__ as_w,
    const float* __restrict__ ad_w, float* __restrict__ as2,
    float* __restrict__ ad2, int n)
{
    int g = threadIdx.x >> 4, c = threadIdx.x & 15;
    int node = blockIdx.x * 16 + g;
    if (node >= n) return;
    ushort2 u = *(const ushort2*)&h2h[(size_t)node * 32 + 2 * c];
    float v0 = h2f(u.x), v1 = h2f(u.y);
    float s = v0 * as_w[2 * c] + v1 * as_w[2 * c + 1];
    float d = v0 * ad_w[2 * c] + v1 * ad_w[2 * c + 1];
    #pragma unroll
    for (int o = 8; o; o >>= 1) { s += __shfl_xor(s, o); d += __shfl_xor(d, o); }
    if (c == 0) { as2[node] = s; ad2[node] = d; }
}

// ============ fused layer-1 GAT: softmax + fp16 gather + ELU ============
__global__ __launch_bounds__(256) void k_gat1(
    const int* __restrict__ row_off, const int* __restrict__ csr,
    const float* __restrict__ as1, const float* __restrict__ ad1,
    const unsigned short* __restrict__ h1h, const float* __restrict__ b1,
    float* __restrict__ z, int n)
{
    int w = threadIdx.x >> 6, lane = threadIdx.x & 63;
    int node = blockIdx.x * 4 + w;
    if (node >= n) return;
    __shared__ int   s_src_all[4][CH1];
    __shared__ float s_p_all[4][CH1 * 4];
    int* ssrc = s_src_all[w];
    float* sp = s_p_all[w];

    float add0 = ad1[(size_t)node * 4 + 0];
    float add1 = ad1[(size_t)node * 4 + 1];
    float add2 = ad1[(size_t)node * 4 + 2];
    float add3 = ad1[(size_t)node * 4 + 3];
    int beg = row_off[node], end = row_off[node + 1];
    int h = lane >> 4;

    float mr0 = -1e30f, mr1 = -1e30f, mr2 = -1e30f, mr3 = -1e30f;
    float sr0 = 0.f, sr1 = 0.f, sr2 = 0.f, sr3 = 0.f;
    float acc0 = 0.f, acc1 = 0.f;

    for (int c = beg; c < end; c += CH1) {
        int cnt = min(CH1, end - c);
        float scA0=-1e30f, scA1=-1e30f, scA2=-1e30f, scA3=-1e30f;
        float scB0=-1e30f, scB1=-1e30f, scB2=-1e30f, scB3=-1e30f;
        bool hasA = lane < cnt, hasB = lane + 64 < cnt;
        if (hasA) {
            int sA = csr[c + lane];
            ssrc[lane] = sA;
            float4 av = *(const float4*)&as1[(size_t)sA * 4];
            float v;
            v = av.x + add0; scA0 = v > 0.f ? v : NEG * v;
            v = av.y + add1; scA1 = v > 0.f ? v : NEG * v;
            v = av.z + add2; scA2 = v > 0.f ? v : NEG * v;
            v = av.w + add3; scA3 = v > 0.f ? v : NEG * v;
        }
        if (hasB) {
            int sB = csr[c + lane + 64];
            ssrc[lane + 64] = sB;
            float4 av = *(const float4*)&as1[(size_t)sB * 4];
            float v;
            v = av.x + add0; scB0 = v > 0.f ? v : NEG * v;
            v = av.y + add1; scB1 = v > 0.f ? v : NEG * v;
            v = av.z + add2; scB2 = v > 0.f ? v : NEG * v;
            v = av.w + add3; scB3 = v > 0.f ? v : NEG * v;
        }
        float lm0 = fmaxf(scA0, scB0), lm1 = fmaxf(scA1, scB1);
        float lm2 = fmaxf(scA2, scB2), lm3 = fmaxf(scA3, scB3);
        #pragma unroll
        for (int o = 32; o; o >>= 1) {
            lm0 = fmaxf(lm0, __shfl_xor(lm0, o));
            lm1 = fmaxf(lm1, __shfl_xor(lm1, o));
            lm2 = fmaxf(lm2, __shfl_xor(lm2, o));
            lm3 = fmaxf(lm3, __shfl_xor(lm3, o));
        }
        float nm0 = fmaxf(mr0, lm0), nm1 = fmaxf(mr1, lm1);
        float nm2 = fmaxf(mr2, lm2), nm3 = fmaxf(mr3, lm3);
        float om  = h == 0 ? mr0 : h == 1 ? mr1 : h == 2 ? mr2 : mr3;
        float nmh = h == 0 ? nm0 : h == 1 ? nm1 : h == 2 ? nm2 : nm3;
        float r = __expf(om - nmh);
        acc0 *= r; acc1 *= r;
        float ls0 = 0.f, ls1 = 0.f, ls2 = 0.f, ls3 = 0.f;
        if (hasA) {
            float p0 = __expf(scA0 - nm0), p1 = __expf(scA1 - nm1);
            float p2 = __expf(scA2 - nm2), p3 = __expf(scA3 - nm3);
            *(float4*)&sp[lane * 4] = make_float4(p0, p1, p2, p3);
            ls0 += p0; ls1 += p1; ls2 += p2; ls3 += p3;
        }
        if (hasB) {
            float p0 = __expf(scB0 - nm0), p1 = __expf(scB1 - nm1);
            float p2 = __expf(scB2 - nm2), p3 = __expf(scB3 - nm3);
            *(float4*)&sp[(lane + 64) * 4] = make_float4(p0, p1, p2, p3);
            ls0 += p0; ls1 += p1; ls2 += p2; ls3 += p3;
        }
        #pragma unroll
        for (int o = 32; o; o >>= 1) {
            ls0 += __shfl_xor(ls0, o);
            ls1 += __shfl_xor(ls1, o);
            ls2 += __shfl_xor(ls2, o);
            ls3 += __shfl_xor(ls3, o);
        }
        sr0 = sr0 * __expf(mr0 - nm0) + ls0;
        sr1 = sr1 * __expf(mr1 - nm1) + ls1;
        sr2 = sr2 * __expf(mr2 - nm2) + ls2;
        sr3 = sr3 * __expf(mr3 - nm3) + ls3;
        __threadfence_block();
        #pragma unroll 4
        for (int j = 0; j < cnt; ++j) {
            int src = ssrc[j];
            float p = sp[j * 4 + h];
            ushort2 u = *(const ushort2*)&h1h[(size_t)src * 128 + 2 * lane];
            acc0 = fmaf(p, h2f(u.x), acc0);
            acc1 = fmaf(p, h2f(u.y), acc1);
        }
        mr0 = nm0; mr1 = nm1; mr2 = nm2; mr3 = nm3;
    }
    float srh = h == 0 ? sr0 : h == 1 ? sr1 : h == 2 ? sr2 : sr3;
    float v0 = acc0 / srh + b1[2 * lane];
    float v1 = acc1 / srh + b1[2 * lane + 1];
    v0 = v0 > 0.f ? v0 : (__expf(v0) - 1.f);
    v1 = v1 > 0.f ? v1 : (__expf(v1) - 1.f);
    *(float2*)&z[(size_t)node * F1 + 2 * lane] = make_float2(v0, v1);
}

// ============ fused layer-2 GAT + log_softmax (fp16 gather) ============
__global__ __launch_bounds__(256) void k_gat2(
    const int* __restrict__ row_off, const int* __restrict__ csr,
    const float* __restrict__ as2, const float* __restrict__ ad2,
    const unsigned short* __restrict__ h2h, const float* __restrict__ b2,
    float* __restrict__ y, int n)
{
    int w = threadIdx.x >> 6, lane = threadIdx.x & 63;
    int node = blockIdx.x * 4 + w;
    if (node >= n) return;
    __shared__ int   s_src_all[4][CH2];
    __shared__ float s_p_all[4][CH2];
    int* ssrc = s_src_all[w];
    float* sp = s_p_all[w];

    float addv = ad2[node];
    int beg = row_off[node], end = row_off[node + 1];
    int c2 = lane & 15, eo = lane >> 4;   // 4 edges in flight
    float mr = -1e30f, sr = 0.f, acc0 = 0.f, acc1 = 0.f;

    for (int c = beg; c < end; c += CH2) {
        int cnt = min(CH2, end - c);
        float scA = -1e30f, scB = -1e30f;
        bool hasA = lane < cnt, hasB = lane + 64 < cnt;
        if (hasA) {
            int sA = csr[c + lane];
            ssrc[lane] = sA;
            float v = as2[sA] + addv;
            scA = v > 0.f ? v : NEG * v;
        }
        if (hasB) {
            int sB = csr[c + lane + 64];
            ssrc[lane + 64] = sB;
            float v = as2[sB] + addv;
            scB = v > 0.f ? v : NEG * v;
        }
        float lm = fmaxf(scA, scB);
        #pragma unroll
        for (int o = 32; o; o >>= 1) lm = fmaxf(lm, __shfl_xor(lm, o));
        float nm = fmaxf(mr, lm);
        float r = __expf(mr - nm);
        acc0 *= r; acc1 *= r; sr *= r;
        float ls = 0.f;
        if (hasA) { float p = __expf(scA - nm); sp[lane] = p; ls += p; }
        if (hasB) { float p = __expf(scB - nm); sp[lane + 64] = p; ls += p; }
        #pragma unroll
        for (int o = 32; o; o >>= 1) ls += __shfl_xor(ls, o);
        sr += ls;
        __threadfence_block();
        #pragma unroll 4
        for (int j = eo; j < cnt; j += 4) {
            int src = ssrc[j];
            float p = sp[j];
            ushort2 u = *(const ushort2*)&h2h[(size_t)src * 32 + 2 * c2];
            acc0 = fmaf(p, h2f(u.x), acc0);
            acc1 = fmaf(p, h2f(u.y), acc1);
        }
        mr = nm;
    }
    acc0 += __shfl_xor(acc0, 16); acc0 += __shfl_xor(acc0, 32);
    acc1 += __shfl_xor(acc1, 16); acc1 += __shfl_xor(acc1, 32);
    float v0 = acc0 / sr + b2[2 * c2];
    float v1 = acc1 / sr + b2[2 * c2 + 1];
    float m = fmaxf(v0, v1);
    #pragma unroll
    for (int o = 8; o; o >>= 1) m = fmaxf(m, __shfl_xor(m, o));
    float ss = __expf(v0 - m) + __expf(v1 - m);
    #pragma unroll
    for (int o = 8; o; o >>= 1) ss += __shfl_xor(ss, o);
    float lg = m + logf(ss);
    if (lane < 16)
        *(float2*)&y[(size_t)node * OUT_C + 2 * c2] = make_float2(v0 - lg, v1 - lg);
}

extern "C" void kernel_launch(void* const* d_in, const int* in_sizes, int n_in,
                              void* d_out, int out_size, void* d_ws, size_t ws_size,
                              hipStream_t stream) {
    const float* x    = (const float*)d_in[0];
    const int*   ei   = (const int*)d_in[1];
    const float* W1   = (const float*)d_in[2];
    const float* as1w = (const float*)d_in[3];
    const float* ad1w = (const float*)d_in[4];
    const float* b1   = (const float*)d_in[5];
    const float* W2   = (const float*)d_in[6];
    const float* as2w = (const float*)d_in[7];
    const float* ad2w = (const float*)d_in[8];
    const float* b2   = (const float*)d_in[9];
    float* out = (float*)d_out;

    int n  = in_sizes[0] / IN_C;
    int E_ = in_sizes[1] / 2;
    int EE = E_ + n;

    int NB = (n + (1 << SH) - 1) >> SH;        // buckets (<=512 for n<=131072)
    int NC = (EE + CHA - 1) / CHA;             // chunks
    int M  = NB * NC;
    int NBLK = (M + SCB - 1) / SCB;            // scan blocks (<=256)

    char* w = (char*)d_ws;
    size_t off = 0;
    auto take = [&](size_t elems) { void* p = w + off; off += ((elems * 4 + 255) & ~(size_t)255); return p; };
    int* bmat      = (int*)take((size_t)M);
    int* bsums     = (int*)take(256);
    unsigned* recs = (unsigned*)take((size_t)EE);
    int* row_off   = (int*)take((size_t)n + 1);
    int* csr       = (int*)take((size_t)EE);
    float* as1     = (float*)take((size_t)n * 4);
    float* ad1     = (float*)take((size_t)n * 4);
    unsigned short* h1h = (unsigned short*)take((size_t)n * 64);  // n*128 fp16
    float* z       = (float*)take((size_t)n * 128);
    unsigned short* h2h = (unsigned short*)take((size_t)n * 16);  // n*32 fp16
    float* as2     = (float*)take((size_t)n);
    float* ad2     = (float*)take((size_t)n);

    // CSR build: bucketed counting sort, no global atomics, parallel scan
    k_bhist   <<<NC, 256, 0, stream>>>(ei, bmat, E_, n, NB, NC);
    k_scanA   <<<NBLK, 256, 0, stream>>>(bmat, bsums, M);
    k_scanB   <<<1, 256, 0, stream>>>(bsums, NBLK);
    k_scanC   <<<(M + 255) / 256, 256, 0, stream>>>(bmat, bsums, M);
    k_bscatter<<<NC, 256, 0, stream>>>(ei, bmat, recs, E_, n, NB, NC);
    k_bfill   <<<NB, 256, 0, stream>>>(recs, bmat, row_off, csr, n, NB, NC, EE);

    // layer 1
    int nt = (n + 63) / 64;
    k_gemm1<<<nt * 2, 256, 0, stream>>>(x, W1, h1h, n);
    k_att1<<<(n + 3) / 4, 256, 0, stream>>>(h1h, as1w, ad1w, as1, ad1, n);
    int gG = (n + 3) / 4;
    k_gat1<<<gG, 256, 0, stream>>>(row_off, csr, as1, ad1, h1h, b1, z, n);

    // layer 2
    k_gemm2<<<nt, 256, 0, stream>>>(z, W2, h2h, n);
    k_att2<<<(n + 15) / 16, 256, 0, stream>>>(h2h, as2w, ad2w, as2, ad2, n);
    k_gat2<<<gG, 256, 0, stream>>>(row_off, csr, as2, ad2, h2h, b2, out, n);
}